// Round 22
// baseline (439.615 us; speedup 1.0000x reference)
//
#include <hip/hip_runtime.h>
#include <hip/hip_bf16.h>
#include <math.h>

#define T_DIM 4096
#define HSZ   7168
#define QLR_K 1536
#define NH    64
#define HD    128
#define QN    (NH*HD)   // 8192
#define TOPK_N 2048
#define MASK_VAL (-3.0e38f)
// 0.125 (w_proj scale) * 128^-0.5 (q scale, folded out of fp8 q for precision)
#define WSCALE 0.011048543456039806f

using short8 = __attribute__((ext_vector_type(8))) short;   // 8 bf16 (4 VGPR)
using f32x4  = __attribute__((ext_vector_type(4))) float;
using i32x8  = __attribute__((ext_vector_type(8))) int;     // fp8 x32 (8 VGPR)

#define MFMA16(a,b,c) __builtin_amdgcn_mfma_f32_16x16x32_bf16(a,b,c,0,0,0)
#define MFMA8(a,b,c)  __builtin_amdgcn_mfma_f32_16x16x32_fp8_fp8(a,b,c,0,0,0)
// MX-scaled K=128 fp8: fmt 0/0 = e4m3/e4m3, scale byte 127 = 2^0 = 1.0.
#define MFMA8S(a,b,c) __builtin_amdgcn_mfma_scale_f32_16x16x128_f8f6f4(a,b,c,0,0,0,127,0,127)

__device__ __forceinline__ float rope_invf(int d) {
    return (float)(1.0 / pow(10000.0, (double)d / 32.0));
}
__device__ __forceinline__ unsigned short f2bf(float f) {
    unsigned u = __float_as_uint(f);
    return (unsigned short)((u + 0x7FFFu + ((u >> 16) & 1u)) >> 16);
}
// HW fp8 e4m3 conversion (v_cvt_pk_fp8_f32, gfx940+)
__device__ __forceinline__ unsigned char f2fp8(float x) {
    return (unsigned char)(__builtin_amdgcn_cvt_pk_fp8_f32(x, x, 0, false) & 0xFF);
}
__device__ __forceinline__ unsigned pk4fp8(float a, float b, float c, float d) {
    unsigned w = (unsigned)__builtin_amdgcn_cvt_pk_fp8_f32(a, b, 0, false);
    return (unsigned)__builtin_amdgcn_cvt_pk_fp8_f32(c, d, (int)w, true);
}

// ============================================================================
// rope_tab
// ============================================================================
__global__ __launch_bounds__(256)
void rope_tab_kernel(const int* __restrict__ positions, float2* __restrict__ tab) {
    int idx = blockIdx.x * 256 + threadIdx.x;
    int t = idx >> 5, dd = idx & 31;
    float p = (float)positions[t];
    float ang = p * rope_invf(dd);
    float s, c; sincosf(ang, &s, &c);
    tab[idx] = make_float2(c, s);
}

// ============================================================================
// conv_afrag (bf16, for hs -> kw path)
// ============================================================================
__global__ __launch_bounds__(256)
void conv_afrag(const float* __restrict__ src, unsigned short* __restrict__ dst,
                int C, int KS, int ctiles) {
    __shared__ float lds[32][258];
    const int tid = threadIdx.x;
    const int rt = blockIdx.x / ctiles, ct = blockIdx.x - rt * ctiles;
    const int r0 = rt * 32, c0 = ct * 256;
#pragma unroll
    for (int it = 0; it < 8; ++it) {
        int fid = it * 256 + tid;
        int r = fid >> 6, c4 = (fid & 63) << 2;
        float4 v = *(const float4*)(src + (size_t)(r0 + r) * C + c0 + c4);
        lds[r][c4] = v.x; lds[r][c4 + 1] = v.y; lds[r][c4 + 2] = v.z; lds[r][c4 + 3] = v.w;
    }
    __syncthreads();
    const int lane = tid & 63, wid = tid >> 6;
#pragma unroll
    for (int j = 0; j < 4; ++j) {
        int s = wid * 4 + j;
        int ig_l = s >> 3, ks_l = s & 7;
        int r = ig_l * 16 + (lane & 15);
        int c = ks_l * 32 + ((lane >> 4) << 3);
        unsigned short o[8];
#pragma unroll
        for (int e = 0; e < 8; ++e) o[e] = f2bf(lds[r][c + e]);
        size_t ig = rt * 2 + ig_l, ks = (size_t)ct * 8 + ks_l;
        *(short8*)(dst + ((ig * KS + ks) * 64 + lane) * 8) = *(short8*)o;
    }
}

// ============================================================================
// conv_qr_fp8: qr f32 -> fp8 A-frag, MX layout [ig][kq 12][lane][32B]
// ============================================================================
__global__ __launch_bounds__(256)
void conv_qr_fp8(const float* __restrict__ src, unsigned char* __restrict__ dst) {
    __shared__ float lds[32][258];
    const int tid = threadIdx.x;
    const int rt = blockIdx.x / 6, ct = blockIdx.x - rt * 6;
    const int r0 = rt * 32, c0 = ct * 256;
#pragma unroll
    for (int it = 0; it < 8; ++it) {
        int fid = it * 256 + tid;
        int r = fid >> 6, c4 = (fid & 63) << 2;
        float4 v = *(const float4*)(src + (size_t)(r0 + r) * QLR_K + c0 + c4);
        lds[r][c4] = v.x; lds[r][c4 + 1] = v.y; lds[r][c4 + 2] = v.z; lds[r][c4 + 3] = v.w;
    }
    __syncthreads();
    const int lane = tid & 63, wid = tid >> 6;
#pragma unroll
    for (int j = 0; j < 4; ++j) {
        int s = wid * 4 + j;
        int ig_l = s >> 3, ks_l = s & 7;
        int r = ig_l * 16 + (lane & 15);
        int c = ks_l * 32 + ((lane >> 4) << 3);
        uint2 o;
        o.x = pk4fp8(lds[r][c], lds[r][c + 1], lds[r][c + 2], lds[r][c + 3]);
        o.y = pk4fp8(lds[r][c + 4], lds[r][c + 5], lds[r][c + 6], lds[r][c + 7]);
        size_t ig = rt * 2 + ig_l;
        int ks = ct * 8 + ks_l;
        size_t off = ((ig * 12 + (ks >> 2)) * 64 + lane) * 32 + (ks & 3) * 8;
        *(uint2*)(dst + off) = o;
    }
}

// ============================================================================
// conv_wq_fp8: wq_b f32 -> fp8 B-frag, MX layout [ng][kq 12][lane][32B]
// ============================================================================
__global__ __launch_bounds__(256)
void conv_wq_fp8(const float* __restrict__ wq, unsigned char* __restrict__ dst) {
    __shared__ float lds[32][258];
    const int tid = threadIdx.x;
    const int kt = blockIdx.x >> 5, nt = blockIdx.x & 31;
    const int k0 = kt * 32, n0 = nt * 256;
#pragma unroll
    for (int it = 0; it < 8; ++it) {
        int fid = it * 256 + tid;
        int k = fid >> 6, c4 = (fid & 63) << 2;
        float4 v = *(const float4*)(wq + (size_t)(k0 + k) * QN + n0 + c4);
        lds[k][c4] = v.x; lds[k][c4 + 1] = v.y; lds[k][c4 + 2] = v.z; lds[k][c4 + 3] = v.w;
    }
    __syncthreads();
    const int lane = tid & 63, wid = tid >> 6;
#pragma unroll
    for (int j = 0; j < 4; ++j) {
        int s = wid * 4 + j;
        int n_l = s * 16 + (lane & 15);
        int kb = (lane >> 4) << 3;
        uint2 o;
        o.x = pk4fp8(lds[kb][n_l], lds[kb + 1][n_l], lds[kb + 2][n_l], lds[kb + 3][n_l]);
        o.y = pk4fp8(lds[kb + 4][n_l], lds[kb + 5][n_l], lds[kb + 6][n_l], lds[kb + 7][n_l]);
        size_t ng = (size_t)nt * 16 + s;
        size_t off = ((ng * 12 + (kt >> 2)) * 64 + lane) * 32 + (kt & 3) * 8;
        *(uint2*)(dst + off) = o;
    }
}

// ============================================================================
// conv_wkw
// ============================================================================
__global__ __launch_bounds__(256)
void conv_wkw(const float* __restrict__ wk, const float* __restrict__ wp,
              unsigned short* __restrict__ dst) {
    int gid = blockIdx.x * 4 + (threadIdx.x >> 6);
    int lane = threadIdx.x & 63;
    int ng = gid / 224, ks = gid - ng * 224;
    int col = ng * 16 + (lane & 15);
    int k = ks * 32 + ((lane >> 4) << 3);
    unsigned short o[8];
#pragma unroll
    for (int e = 0; e < 8; ++e) {
        float v = (col < 128) ? wk[(size_t)(k + e) * 128 + col]
                              : wp[(size_t)(k + e) * 64 + (col - 128)];
        o[e] = f2bf(v);
    }
    *(short8*)(dst + ((size_t)gid * 64 + lane) * 8) = *(short8*)o;
}

// ============================================================================
// kw_gemm_mfma v2 (verified round 13)
// ============================================================================
__global__ __launch_bounds__(256, 4)
void kw_gemm_mfma(const unsigned short* __restrict__ hsfrag,
                  const unsigned short* __restrict__ wkwfrag,
                  float* __restrict__ part) {
    const int kz = blockIdx.x >> 8;              // 0..3
    const int ig = blockIdx.x & 255;             // 0..255
    const int lane = threadIdx.x & 63, wid = threadIdx.x >> 6;
    const f32x4 zed = {0.f, 0.f, 0.f, 0.f};
    f32x4 acc[3];
#pragma unroll
    for (int j = 0; j < 3; ++j) acc[j] = zed;

    const unsigned short* ap = hsfrag + ((size_t)ig * 224 * 64 + lane) * 8;
    const unsigned short* bp = wkwfrag + ((size_t)(wid * 3) * 224 * 64 + lane) * 8;
#pragma unroll 4
    for (int ks = kz * 56; ks < kz * 56 + 56; ++ks) {
        short8 a = *(const short8*)(ap + (size_t)ks * 512);
        short8 b0 = *(const short8*)(bp + (size_t)ks * 512);
        short8 b1 = *(const short8*)(bp + (size_t)(224 * 64 * 8) + (size_t)ks * 512);
        short8 b2 = *(const short8*)(bp + (size_t)(2 * 224 * 64 * 8) + (size_t)ks * 512);
        acc[0] = MFMA16(a, b0, acc[0]);
        acc[1] = MFMA16(a, b1, acc[1]);
        acc[2] = MFMA16(a, b2, acc[2]);
    }
    const int colc = lane & 15, rsub = (lane >> 4) << 2;
    float* pb = part + (size_t)kz * T_DIM * 192;
#pragma unroll
    for (int j = 0; j < 3; ++j) {
        int ng = wid * 3 + j;
#pragma unroll
        for (int r = 0; r < 4; ++r) {
            int row = ig * 16 + rsub + r;
            pb[(size_t)row * 192 + ng * 16 + colc] = acc[j][r];
        }
    }
}

// ============================================================================
// reduce_w
// ============================================================================
__global__ __launch_bounds__(256)
void reduce_w(const float* __restrict__ part, float* __restrict__ wT) {
    __shared__ float lds[64][65];
    const int r0 = blockIdx.x * 64;
    const int tid = threadIdx.x;
#pragma unroll
    for (int it = 0; it < 16; ++it) {
        int fid = it * 256 + tid;
        int rl = fid >> 6, h = fid & 63;
        float s = 0.f;
#pragma unroll
        for (int z = 0; z < 4; ++z)
            s += part[((size_t)z * T_DIM + r0 + rl) * 192 + 128 + h];
        lds[rl][h] = s * WSCALE;
    }
    __syncthreads();
#pragma unroll
    for (int it = 0; it < 16; ++it) {
        int fid = it * 256 + tid;
        int h = fid >> 6, rl = fid & 63;
        wT[(size_t)h * T_DIM + r0 + rl] = lds[rl][h];
    }
}

// ============================================================================
// ln_rope_k: reduce + LN + rope; fp8 kfrag layout [jg][lane][32B]
// ============================================================================
__global__ __launch_bounds__(256)
void ln_rope_k(const float* __restrict__ part, const float2* __restrict__ tab,
               const float* __restrict__ gamma, const float* __restrict__ beta,
               unsigned char* __restrict__ kfrag) {
    __shared__ float ln[4][128];
    const int tid = threadIdx.x;
    const int wr = tid >> 6, lane = tid & 63;
    const int row = blockIdx.x * 4 + wr;
    float2 v = make_float2(0.f, 0.f);
#pragma unroll
    for (int z = 0; z < 4; ++z) {
        float2 p = *(const float2*)(part + ((size_t)z * T_DIM + row) * 192 + lane * 2);
        v.x += p.x; v.y += p.y;
    }
    float s = v.x + v.y;
#pragma unroll
    for (int off = 1; off < 64; off <<= 1) s += __shfl_xor(s, off);
    float mu = s * (1.0f / 128.0f);
    float d0 = v.x - mu, d1 = v.y - mu;
    float s2 = d0 * d0 + d1 * d1;
#pragma unroll
    for (int off = 1; off < 64; off <<= 1) s2 += __shfl_xor(s2, off);
    float rstd = 1.0f / sqrtf(s2 * (1.0f / 128.0f) + 1e-6f);
    ln[wr][lane * 2]     = d0 * rstd * gamma[lane * 2]     + beta[lane * 2];
    ln[wr][lane * 2 + 1] = d1 * rstd * gamma[lane * 2 + 1] + beta[lane * 2 + 1];
    __syncthreads();
    int d = lane * 2;
    float o0, o1;
    float v0 = ln[wr][d], v1 = ln[wr][d + 1];
    if (d < 64) {
        int dd = d & 31;
        float2 c0 = tab[(size_t)row * 32 + dd];
        float2 c1 = tab[(size_t)row * 32 + dd + 1];
        if (d < 32) {
            o0 = v0 * c0.x - ln[wr][d + 32] * c0.y;
            o1 = v1 * c1.x - ln[wr][d + 33] * c1.y;
        } else {
            o0 = v0 * c0.x + ln[wr][d - 32] * c0.y;
            o1 = v1 * c1.x + ln[wr][d - 31] * c1.y;
        }
    } else { o0 = v0; o1 = v1; }
    int jg = row >> 4, ks = d >> 5, sub = d & 31;
    int lp = ((sub >> 3) << 4) + (row & 15);
    size_t bidx = ((size_t)jg * 64 + lp) * 32 + ks * 8 + (sub & 7);
    unsigned pk = (unsigned)__builtin_amdgcn_cvt_pk_fp8_f32(o0, o1, 0, false);
    *(unsigned short*)(kfrag + bidx) = (unsigned short)(pk & 0xFFFFu);
}

// ============================================================================
// q_gemm_mfma v4 (verified round 19): MX K=128, minimal operand liveness.
// ============================================================================
__global__ __launch_bounds__(256, 2)
void q_gemm_mfma(const unsigned char* __restrict__ qr8,
                 const unsigned char* __restrict__ wq8,
                 const float2* __restrict__ tab,
                 unsigned char* __restrict__ qfrag) {
    const int hw = blockIdx.x;
    const int orig = (hw & 7) * 256 + (hw >> 3);
    const int head = orig >> 5, mt = orig & 31;
    const int tid = threadIdx.x, lane = tid & 63, wid = tid >> 6;
    const int wm = wid >> 1, wn = wid & 1;
    const f32x4 zed = {0.f, 0.f, 0.f, 0.f};
    f32x4 acc[4][4];
#pragma unroll
    for (int m = 0; m < 4; m++)
#pragma unroll
        for (int n = 0; n < 4; n++) acc[m][n] = zed;

    const int ig0 = mt * 8 + wm * 4;
    const int ng0 = head * 8 + wn * 4;
    const unsigned char* ap = qr8 + ((size_t)ig0 * 12 * 64 + lane) * 32;
    const unsigned char* bp = wq8 + ((size_t)ng0 * 12 * 64 + lane) * 32;
    for (int kq = 0; kq < 12; ++kq) {
        i32x8 a0_ = *(const i32x8*)(ap + (size_t)(0 * 12 + kq) * 2048);
        i32x8 a1_ = *(const i32x8*)(ap + (size_t)(1 * 12 + kq) * 2048);
        i32x8 a2_ = *(const i32x8*)(ap + (size_t)(2 * 12 + kq) * 2048);
        i32x8 a3_ = *(const i32x8*)(ap + (size_t)(3 * 12 + kq) * 2048);
#pragma unroll
        for (int n = 0; n < 4; n++) {
            i32x8 b = *(const i32x8*)(bp + ((size_t)n * 12 + kq) * 2048);
            acc[0][n] = MFMA8S(a0_, b, acc[0][n]);
            acc[1][n] = MFMA8S(a1_, b, acc[1][n]);
            acc[2][n] = MFMA8S(a2_, b, acc[2][n]);
            acc[3][n] = MFMA8S(a3_, b, acc[3][n]);
        }
    }
    const int colc = lane & 15;
    const int rsub = (lane >> 4) << 2;
#pragma unroll
    for (int m = 0; m < 4; m++) {
#pragma unroll
        for (int r = 0; r < 4; r++) {
            int row = mt * 128 + wm * 64 + m * 16 + rsub + r;
            int rl = rsub + r;
            size_t base = ((size_t)(row >> 4) * 64 + head) * 2048;
            if (wn == 0) {
#pragma unroll
                for (int n2 = 0; n2 < 2; n2++) {
                    int dd = n2 * 16 + colc;
                    float2 cs = tab[(size_t)row * 32 + dd];
                    float x1 = acc[m][n2][r], x2 = acc[m][n2 + 2][r];
                    float olo = x1 * cs.x - x2 * cs.y;
                    float ohi = x2 * cs.x + x1 * cs.y;
                    int lp = ((dd >> 3) << 4) + rl;
                    qfrag[base + lp * 32 + 0 * 8 + (dd & 7)] = f2fp8(olo);
                    qfrag[base + lp * 32 + 1 * 8 + (dd & 7)] = f2fp8(ohi);
                }
            } else {
#pragma unroll
                for (int n = 0; n < 4; n++) {
                    int d = 64 + n * 16 + colc;
                    int ks2 = d >> 5, sub = d & 31;
                    int lp = ((sub >> 3) << 4) + rl;
                    qfrag[base + lp * 32 + ks2 * 8 + (sub & 7)] = f2fp8(acc[m][n][r]);
                }
            }
        }
    }
}

// ============================================================================
// scores_mfma v12: v11 + 4-deep register Q prefetch. Round-21 counters
// refuted BW-bound (halving traffic gave -8%); model says per-h exposed
// L3 latency (~600cyc vs ~200cyc compute, 1-deep prefetch) is the wall.
// Loads now issue 3 h ahead (~600cyc cover). Tail prefetches (h+4..h+6
// >= 64) read a few KB past this ig's slice into adjacent workspace --
// allocated, unused. All buffers named scalars (rule #20).
// ============================================================================
#define SCOMP(A, hh) {                                                         \
    f32x4 s0 = MFMA8S(A, kf8[0], zed);                                         \
    f32x4 s1 = MFMA8S(A, kf8[1], zed);                                         \
    f32x4 s2 = MFMA8S(A, kf8[2], zed);                                         \
    f32x4 s3 = MFMA8S(A, kf8[3], zed);                                         \
    f32x4 s4 = MFMA8S(A, kf8[4], zed);                                         \
    f32x4 s5 = MFMA8S(A, kf8[5], zed);                                         \
    f32x4 s6 = MFMA8S(A, kf8[6], zed);                                         \
    f32x4 s7 = MFMA8S(A, kf8[7], zed);                                         \
    f32x4 wv = *(const f32x4*)&wlds[hh][wid * 16 + rsub];                      \
    _Pragma("unroll")                                                          \
    for (int rr_ = 0; rr_ < 4; ++rr_) {                                        \
        acc[0][rr_] += wv[rr_] * fmaxf(s0[rr_], 0.0f);                         \
        acc[1][rr_] += wv[rr_] * fmaxf(s1[rr_], 0.0f);                         \
        acc[2][rr_] += wv[rr_] * fmaxf(s2[rr_], 0.0f);                         \
        acc[3][rr_] += wv[rr_] * fmaxf(s3[rr_], 0.0f);                         \
        acc[4][rr_] += wv[rr_] * fmaxf(s4[rr_], 0.0f);                         \
        acc[5][rr_] += wv[rr_] * fmaxf(s5[rr_], 0.0f);                         \
        acc[6][rr_] += wv[rr_] * fmaxf(s6[rr_], 0.0f);                         \
        acc[7][rr_] += wv[rr_] * fmaxf(s7[rr_], 0.0f);                         \
    }                                                                          \
}

__global__ __launch_bounds__(256)
void scores_mfma(const unsigned char* __restrict__ qfrag,
                 const unsigned char* __restrict__ kfrag,
                 const float* __restrict__ wT, float* __restrict__ S) {
    const int bid = blockIdx.x;                  // 0..1055
    int u = (int)((sqrtf(4.f * bid + 1.f) - 1.f) * 0.5f);
    while ((u + 1) * (u + 2) <= bid) ++u;
    while (u * (u + 1) > bid) --u;
    int r_ = bid - u * (u + 1);                  // 0..2u+1
    const int byp = (r_ <= u) ? 2 * u : 2 * u + 1;
    const int jt  = (r_ <= u) ? r_ : r_ - (u + 1);
    __shared__ float wlds[64][64];
    const int tid = threadIdx.x;
    const int lane = tid & 63, wid = tid >> 6;   // wave = ig owner (0..3)
    const int i0 = byp * 64, j0 = jt * 128;
    const f32x4 zed = {0.f, 0.f, 0.f, 0.f};
#pragma unroll
    for (int it = 0; it < 16; ++it) {
        int fid = it * 256 + tid;
        int hh = fid >> 6, rl = fid & 63;
        wlds[hh][rl] = wT[(size_t)hh * T_DIM + i0 + rl];
    }
    i32x8 kf8[8];
#pragma unroll
    for (int n = 0; n < 8; ++n) {
        int jg = (j0 >> 4) + n;
        kf8[n] = *(const i32x8*)(kfrag + ((size_t)jg * 64 + lane) * 32);
    }
    __syncthreads();

    f32x4 acc[8];
#pragma unroll
    for (int n = 0; n < 8; n++) acc[n] = zed;

    const int rsub = (lane >> 4) << 2;
    const unsigned char* qb = qfrag + (size_t)(byp * 4 + wid) * 131072 + lane * 32;

    i32x8 a0 = *(const i32x8*)(qb + 0 * 2048);
    i32x8 a1 = *(const i32x8*)(qb + 1 * 2048);
    i32x8 a2 = *(const i32x8*)(qb + 2 * 2048);
    i32x8 a3;
    for (int h = 0; h < NH; h += 4) {
        a3 = *(const i32x8*)(qb + (size_t)(h + 3) * 2048);
        SCOMP(a0, h)
        a0 = *(const i32x8*)(qb + (size_t)(h + 4) * 2048);
        SCOMP(a1, h + 1)
        a1 = *(const i32x8*)(qb + (size_t)(h + 5) * 2048);
        SCOMP(a2, h + 2)
        a2 = *(const i32x8*)(qb + (size_t)(h + 6) * 2048);
        SCOMP(a3, h + 3)
    }

    const int colc = lane & 15;
#pragma unroll
    for (int n = 0; n < 8; n++) {
        int col = j0 + n * 16 + colc;
#pragma unroll
        for (int rr = 0; rr < 4; rr++) {
            int row = i0 + wid * 16 + rsub + rr;
            float v = acc[n][rr];
            if (col > row) v = MASK_VAL;
            S[(size_t)row * T_DIM + col] = v;
        }
    }
}

// ============================================================================
// topk v7: E=8 keys/thread bitonic (verified round 21)
// ============================================================================
__device__ __forceinline__ void ce(unsigned &x, unsigned &y, bool up) {
    unsigned lo = x < y ? x : y, hi = x < y ? y : x;
    x = up ? lo : hi; y = up ? hi : lo;
}
__device__ __forceinline__ unsigned cd(unsigned a, unsigned b, bool keep_lo) {
    unsigned lo = a < b ? a : b, hi = a < b ? b : a;
    return keep_lo ? lo : hi;
}

#define CE8S(k, j) {                                                           \
    const bool kl_ = ((e0 & (k)) == 0u) ^ ((e0 & (j)) != 0u);                  \
    q0 = cd(q0, (unsigned)__shfl_xor((int)q0, (j) >> 3), kl_);                 \
    q1 = cd(q1, (unsigned)__shfl_xor((int)q1, (j) >> 3), kl_);                 \
    q2 = cd(q2, (unsigned)__shfl_xor((int)q2, (j) >> 3), kl_);                 \
    q3 = cd(q3, (unsigned)__shfl_xor((int)q3, (j) >> 3), kl_);                 \
    q4 = cd(q4, (unsigned)__shfl_xor((int)q4, (j) >> 3), kl_);                 \
    q5 = cd(q5, (unsigned)__shfl_xor((int)q5, (j) >> 3), kl_);                 \
    q6 = cd(q6, (unsigned)__shfl_xor((int)q6, (j) >> 3), kl_);                 \
    q7 = cd(q7, (unsigned)__shfl_xor((int)q7, (j) >> 3), kl_); }

#define CE8R(k) {                                                              \
    const bool up_ = ((e0 & (k)) == 0u);                                       \
    ce(q0, q4, up_); ce(q1, q5, up_); ce(q2, q6, up_); ce(q3, q7, up_);        \
    ce(q0, q2, up_); ce(q1, q3, up_); ce(q4, q6, up_); ce(q5, q7, up_);        \
    ce(q0, q1, up_); ce(q2, q3, up_); ce(q4, q5, up_); ce(q6, q7, up_); }

#define CE8L(k, j) {                                                           \
    __syncthreads();                                                           \
    *(uint4*)&L[e0]     = make_uint4(q0, q1, q2, q3);                          \
    *(uint4*)&L[e0 + 4] = make_uint4(q4, q5, q6, q7);                          \
    __syncthreads();                                                           \
    uint4 pA_ = *(uint4*)&L[(e0 ^ (j))];                                       \
    uint4 pB_ = *(uint4*)&L[(e0 ^ (j)) + 4];                                   \
    const bool kl_ = ((e0 & (k)) == 0u) ^ ((e0 & (j)) != 0u);                  \
    q0 = cd(q0, pA_.x, kl_); q1 = cd(q1, pA_.y, kl_);                          \
    q2 = cd(q2, pA_.z, kl_); q3 = cd(q3, pA_.w, kl_);                          \
    q4 = cd(q4, pB_.x, kl_); q5 = cd(q5, pB_.y, kl_);                          \
    q6 = cd(q6, pB_.z, kl_); q7 = cd(q7, pB_.w, kl_); }

#define CM8L(j) {                                                              \
    __syncthreads();                                                           \
    if (low) {                                                                 \
        *(uint4*)&L[e0]     = make_uint4(q0, q1, q2, q3);                      \
        *(uint4*)&L[e0 + 4] = make_uint4(q4, q5, q6, q7);                      \
    }                                                                          \
    __syncthreads();                                                           \
    if (low) {                                                                 \
        uint4 pA_ = *(uint4*)&L[(e0 ^ (j))];                                   \
        uint4 pB_ = *(uint4*)&L[(e0 ^ (j)) + 4];                               \
        const bool kl_ = (e0 & (j)) == 0u;                                     \
        q0 = cd(q0, pA_.x, kl_); q1 = cd(q1, pA_.y, kl_);                      \
        q2 = cd(q2, pA_.z, kl_); q3 = cd(q3, pA_.w, kl_);                      \
        q4 = cd(q4, pB_.x, kl_); q5 = cd(q5, pB_.y, kl_);                      \
        q6 = cd(q6, pB_.z, kl_); q7 = cd(q7, pB_.w, kl_); } }

#define CM8S(j) {                                                              \
    const bool kl_ = (e0 & (j)) == 0u;                                         \
    q0 = cd(q0, (unsigned)__shfl_xor((int)q0, (j) >> 3), kl_);                 \
    q1 = cd(q1, (unsigned)__shfl_xor((int)q1, (j) >> 3), kl_);                 \
    q2 = cd(q2, (unsigned)__shfl_xor((int)q2, (j) >> 3), kl_);                 \
    q3 = cd(q3, (unsigned)__shfl_xor((int)q3, (j) >> 3), kl_);                 \
    q4 = cd(q4, (unsigned)__shfl_xor((int)q4, (j) >> 3), kl_);                 \
    q5 = cd(q5, (unsigned)__shfl_xor((int)q5, (j) >> 3), kl_);                 \
    q6 = cd(q6, (unsigned)__shfl_xor((int)q6, (j) >> 3), kl_);                 \
    q7 = cd(q7, (unsigned)__shfl_xor((int)q7, (j) >> 3), kl_); }

__global__ __launch_bounds__(1024)
void topk_kernel(const float* __restrict__ S, float* __restrict__ outIdx) {
    __shared__ unsigned lds[8192];
    const int bid = blockIdx.x;
    const int tid = threadIdx.x;

    int row; unsigned e0; unsigned* L; bool longrow;
    if (bid < 512) {             // 4 short rows (row < 2048), 256 thr each
        int slot = tid >> 8;
        row = bid * 4 + slot;
        e0 = 8u * (tid & 255);
        L = &lds[slot * 2048];
        longrow = false;
    } else {                     // 2 long rows, 512 thr each
        int slot = tid >> 9;
        row = 2048 + (bid - 512) * 2 + slot;
        e0 = 8u * (tid & 511);
        L = &lds[slot * 4096];
        longrow = true;
    }

    unsigned q0, q1, q2, q3, q4, q5, q6, q7;
    {   // load 8 keys + mask synth
        float4 f0 = *(const float4*)(S + (size_t)row * T_DIM + e0);
        float4 f1 = *(const float4*)(S + (size_t)row * T_DIM + e0 + 4);
        const float fp[8] = {f0.x, f0.y, f0.z, f0.w, f1.x, f1.y, f1.z, f1.w};
        unsigned qq[8];
#pragma unroll
        for (int e = 0; e < 8; ++e) {
            unsigned p = e0 + e;
            unsigned u = __float_as_uint(fp[e]);
            u = (u & 0x80000000u) ? ~u : (u | 0x80000000u);
            unsigned key = ((~u) & 0xFFFFF000u) | p;
            qq[e] = ((int)p > row) ? (0xFFFFF000u | p) : key;
        }
        q0 = qq[0]; q1 = qq[1]; q2 = qq[2]; q3 = qq[3];
        q4 = qq[4]; q5 = qq[5]; q6 = qq[6]; q7 = qq[7];
    }
    // in-thread stages k=2,4,8 (directions from global index bits)
    ce(q0, q1, true);  ce(q2, q3, false); ce(q4, q5, true);  ce(q6, q7, false);
    ce(q0, q2, true);  ce(q1, q3, true);  ce(q4, q6, false); ce(q5, q7, false);
    ce(q0, q1, true);  ce(q2, q3, true);  ce(q4, q5, false); ce(q6, q7, false);
    {
        const bool up8 = ((e0 & 8u) == 0u);
        ce(q0, q4, up8); ce(q1, q5, up8); ce(q2, q6, up8); ce(q3, q7, up8);
        ce(q0, q2, up8); ce(q1, q3, up8); ce(q4, q6, up8); ce(q5, q7, up8);
        ce(q0, q1, up8); ce(q2, q3, up8); ce(q4, q5, up8); ce(q6, q7, up8);
    }
    // stages k=16..2048
    CE8S(16u, 8u)                                                CE8R(16u)
    CE8S(32u, 16u)  CE8S(32u, 8u)                                CE8R(32u)
    CE8S(64u, 32u)  CE8S(64u, 16u)  CE8S(64u, 8u)                CE8R(64u)
    CE8S(128u, 64u) CE8S(128u, 32u) CE8S(128u, 16u) CE8S(128u, 8u) CE8R(128u)
    CE8S(256u, 128u) CE8S(256u, 64u) CE8S(256u, 32u)
    CE8S(256u, 16u)  CE8S(256u, 8u)                              CE8R(256u)
    CE8S(512u, 256u) CE8S(512u, 128u) CE8S(512u, 64u)
    CE8S(512u, 32u)  CE8S(512u, 16u)  CE8S(512u, 8u)             CE8R(512u)
    CE8L(1024u, 512u)
    CE8S(1024u, 256u) CE8S(1024u, 128u) CE8S(1024u, 64u)
    CE8S(1024u, 32u)  CE8S(1024u, 16u)  CE8S(1024u, 8u)          CE8R(1024u)
    CE8L(2048u, 1024u) CE8L(2048u, 512u)
    CE8S(2048u, 256u) CE8S(2048u, 128u) CE8S(2048u, 64u)
    CE8S(2048u, 32u)  CE8S(2048u, 16u)  CE8S(2048u, 8u)          CE8R(2048u)

    if (!longrow) {
        float4 o0 = make_float4((float)(q0 & 0xFFFu), (float)(q1 & 0xFFFu),
                                (float)(q2 & 0xFFFu), (float)(q3 & 0xFFFu));
        float4 o1 = make_float4((float)(q4 & 0xFFFu), (float)(q5 & 0xFFFu),
                                (float)(q6 & 0xFFFu), (float)(q7 & 0xFFFu));
        *(float4*)(outIdx + (size_t)row * TOPK_N + e0) = o0;
        *(float4*)(outIdx + (size_t)row * TOPK_N + e0 + 4) = o1;
    } else {
        // merge k=4096: mins into lower 2048, then ascending clean of lower.
        __syncthreads();
        *(uint4*)&L[e0]     = make_uint4(q0, q1, q2, q3);
        *(uint4*)&L[e0 + 4] = make_uint4(q4, q5, q6, q7);
        __syncthreads();
        const bool low = e0 < 2048u;
        if (low) {
            uint4 pA = *(uint4*)&L[e0 + 2048];
            uint4 pB = *(uint4*)&L[e0 + 2048 + 4];
            q0 = q0 < pA.x ? q0 : pA.x; q1 = q1 < pA.y ? q1 : pA.y;
            q2 = q2 < pA.z ? q2 : pA.z; q3 = q3 < pA.w ? q3 : pA.w;
            q4 = q4 < pB.x ? q4 : pB.x; q5 = q5 < pB.y ? q5 : pB.y;
            q6 = q6 < pB.z ? q6 : pB.z; q7 = q7 < pB.w ? q7 : pB.w;
        }
        CM8L(1024u) CM8L(512u)
        if (low) {
            CM8S(256u) CM8S(128u) CM8S(64u) CM8S(32u) CM8S(16u) CM8S(8u)
            ce(q0, q4, true); ce(q1, q5, true); ce(q2, q6, true); ce(q3, q7, true);
            ce(q0, q2, true); ce(q1, q3, true); ce(q4, q6, true); ce(q5, q7, true);
            ce(q0, q1, true); ce(q2, q3, true); ce(q4, q5, true); ce(q6, q7, true);
            float4 o0 = make_float4((float)(q0 & 0xFFFu), (float)(q1 & 0xFFFu),
                                    (float)(q2 & 0xFFFu), (float)(q3 & 0xFFFu));
            float4 o1 = make_float4((float)(q4 & 0xFFFu), (float)(q5 & 0xFFFu),
                                    (float)(q6 & 0xFFFu), (float)(q7 & 0xFFFu));
            *(float4*)(outIdx + (size_t)row * TOPK_N + e0) = o0;
            *(float4*)(outIdx + (size_t)row * TOPK_N + e0 + 4) = o1;
        }
    }
}

// ============================================================================
extern "C" void kernel_launch(void* const* d_in, const int* in_sizes, int n_in,
                              void* d_out, int out_size, void* d_ws, size_t ws_size,
                              hipStream_t stream) {
    const float* hs      = (const float*)d_in[0];
    const float* qr      = (const float*)d_in[1];
    const int*   pos     = (const int*)  d_in[2];
    const float* wq_b    = (const float*)d_in[3];
    const float* wk      = (const float*)d_in[4];
    const float* k_gamma = (const float*)d_in[5];
    const float* k_beta  = (const float*)d_in[6];
    const float* w_proj  = (const float*)d_in[7];

    float* out     = (float*)d_out;
    float* out_idx = out;
    float* S       = out + (size_t)T_DIM * TOPK_N;

    char* wsp = (char*)d_ws;
    unsigned char*  qfrag  = (unsigned char*)wsp;  wsp += (size_t)67108864;
    unsigned short* hsfrag = (unsigned short*)qfrag;  // alias: hs consumed before qfrag written
    unsigned char*  qrfrag = (unsigned char*)wsp;  wsp += (size_t)12582912;
    unsigned char*  wqfrag = (unsigned char*)wsp;  wsp += (size_t)25165824;
    unsigned short* wkwfrag= (unsigned short*)wsp; wsp += (size_t)2752512;
    float*          part   = (float*)wsp;          wsp += (size_t)12582912;
    float*          wT     = (float*)wsp;          wsp += (size_t)1048576;
    unsigned char*  kfrag  = (unsigned char*)wsp;  wsp += (size_t)1048576;
    float2*         tab    = (float2*)wsp;         wsp += (size_t)1048576;

    rope_tab_kernel<<<512, 256, 0, stream>>>(pos, tab);
    conv_afrag <<<3584, 256, 0, stream>>>(hs, hsfrag, HSZ, 224, 28);
    conv_wkw   <<<672,  256, 0, stream>>>(wk, w_proj, wkwfrag);
    kw_gemm_mfma<<<1024, 256, 0, stream>>>(hsfrag, wkwfrag, part);
    reduce_w   <<<64,   256, 0, stream>>>(part, wT);
    ln_rope_k  <<<T_DIM / 4, 256, 0, stream>>>(part, tab, k_gamma, k_beta, kfrag);
    conv_qr_fp8<<<768,  256, 0, stream>>>(qr, qrfrag);
    conv_wq_fp8<<<1536, 256, 0, stream>>>(wq_b, wqfrag);
    q_gemm_mfma<<<2048, 256, 0, stream>>>(qrfrag, wqfrag, tab, qfrag);
    scores_mfma<<<1056, 256, 0, stream>>>(qfrag, kfrag, wT, S);
    topk_kernel<<<1536, 1024, 0, stream>>>(S, out_idx);
}

// Round 23
// 438.897 us; speedup vs baseline: 1.0016x; 1.0016x over previous
//
#include <hip/hip_runtime.h>
#include <hip/hip_bf16.h>
#include <math.h>

#define T_DIM 4096
#define HSZ   7168
#define QLR_K 1536
#define NH    64
#define HD    128
#define QN    (NH*HD)   // 8192
#define TOPK_N 2048
#define MASK_VAL (-3.0e38f)
// 0.125 (w_proj scale) * 128^-0.5 (q scale, folded out of fp8 q for precision)
#define WSCALE 0.011048543456039806f

using short8 = __attribute__((ext_vector_type(8))) short;   // 8 bf16 (4 VGPR)
using f32x4  = __attribute__((ext_vector_type(4))) float;
using i32x8  = __attribute__((ext_vector_type(8))) int;     // fp8 x32 (8 VGPR)

#define MFMA16(a,b,c) __builtin_amdgcn_mfma_f32_16x16x32_bf16(a,b,c,0,0,0)
#define MFMA8(a,b,c)  __builtin_amdgcn_mfma_f32_16x16x32_fp8_fp8(a,b,c,0,0,0)
// MX-scaled K=128 fp8: fmt 0/0 = e4m3/e4m3, scale byte 127 = 2^0 = 1.0.
#define MFMA8S(a,b,c) __builtin_amdgcn_mfma_scale_f32_16x16x128_f8f6f4(a,b,c,0,0,0,127,0,127)

__device__ __forceinline__ float rope_invf(int d) {
    return (float)(1.0 / pow(10000.0, (double)d / 32.0));
}
__device__ __forceinline__ unsigned short f2bf(float f) {
    unsigned u = __float_as_uint(f);
    return (unsigned short)((u + 0x7FFFu + ((u >> 16) & 1u)) >> 16);
}
// HW fp8 e4m3 conversion (v_cvt_pk_fp8_f32, gfx940+)
__device__ __forceinline__ unsigned char f2fp8(float x) {
    return (unsigned char)(__builtin_amdgcn_cvt_pk_fp8_f32(x, x, 0, false) & 0xFF);
}
__device__ __forceinline__ unsigned pk4fp8(float a, float b, float c, float d) {
    unsigned w = (unsigned)__builtin_amdgcn_cvt_pk_fp8_f32(a, b, 0, false);
    return (unsigned)__builtin_amdgcn_cvt_pk_fp8_f32(c, d, (int)w, true);
}

// ============================================================================
// rope_tab
// ============================================================================
__global__ __launch_bounds__(256)
void rope_tab_kernel(const int* __restrict__ positions, float2* __restrict__ tab) {
    int idx = blockIdx.x * 256 + threadIdx.x;
    int t = idx >> 5, dd = idx & 31;
    float p = (float)positions[t];
    float ang = p * rope_invf(dd);
    float s, c; sincosf(ang, &s, &c);
    tab[idx] = make_float2(c, s);
}

// ============================================================================
// conv_afrag (bf16, for hs -> kw path)
// ============================================================================
__global__ __launch_bounds__(256)
void conv_afrag(const float* __restrict__ src, unsigned short* __restrict__ dst,
                int C, int KS, int ctiles) {
    __shared__ float lds[32][258];
    const int tid = threadIdx.x;
    const int rt = blockIdx.x / ctiles, ct = blockIdx.x - rt * ctiles;
    const int r0 = rt * 32, c0 = ct * 256;
#pragma unroll
    for (int it = 0; it < 8; ++it) {
        int fid = it * 256 + tid;
        int r = fid >> 6, c4 = (fid & 63) << 2;
        float4 v = *(const float4*)(src + (size_t)(r0 + r) * C + c0 + c4);
        lds[r][c4] = v.x; lds[r][c4 + 1] = v.y; lds[r][c4 + 2] = v.z; lds[r][c4 + 3] = v.w;
    }
    __syncthreads();
    const int lane = tid & 63, wid = tid >> 6;
#pragma unroll
    for (int j = 0; j < 4; ++j) {
        int s = wid * 4 + j;
        int ig_l = s >> 3, ks_l = s & 7;
        int r = ig_l * 16 + (lane & 15);
        int c = ks_l * 32 + ((lane >> 4) << 3);
        unsigned short o[8];
#pragma unroll
        for (int e = 0; e < 8; ++e) o[e] = f2bf(lds[r][c + e]);
        size_t ig = rt * 2 + ig_l, ks = (size_t)ct * 8 + ks_l;
        *(short8*)(dst + ((ig * KS + ks) * 64 + lane) * 8) = *(short8*)o;
    }
}

// ============================================================================
// conv_qr_fp8: qr f32 -> fp8 A-frag, MX layout [ig][kq 12][lane][32B]
// ============================================================================
__global__ __launch_bounds__(256)
void conv_qr_fp8(const float* __restrict__ src, unsigned char* __restrict__ dst) {
    __shared__ float lds[32][258];
    const int tid = threadIdx.x;
    const int rt = blockIdx.x / 6, ct = blockIdx.x - rt * 6;
    const int r0 = rt * 32, c0 = ct * 256;
#pragma unroll
    for (int it = 0; it < 8; ++it) {
        int fid = it * 256 + tid;
        int r = fid >> 6, c4 = (fid & 63) << 2;
        float4 v = *(const float4*)(src + (size_t)(r0 + r) * QLR_K + c0 + c4);
        lds[r][c4] = v.x; lds[r][c4 + 1] = v.y; lds[r][c4 + 2] = v.z; lds[r][c4 + 3] = v.w;
    }
    __syncthreads();
    const int lane = tid & 63, wid = tid >> 6;
#pragma unroll
    for (int j = 0; j < 4; ++j) {
        int s = wid * 4 + j;
        int ig_l = s >> 3, ks_l = s & 7;
        int r = ig_l * 16 + (lane & 15);
        int c = ks_l * 32 + ((lane >> 4) << 3);
        uint2 o;
        o.x = pk4fp8(lds[r][c], lds[r][c + 1], lds[r][c + 2], lds[r][c + 3]);
        o.y = pk4fp8(lds[r][c + 4], lds[r][c + 5], lds[r][c + 6], lds[r][c + 7]);
        size_t ig = rt * 2 + ig_l;
        int ks = ct * 8 + ks_l;
        size_t off = ((ig * 12 + (ks >> 2)) * 64 + lane) * 32 + (ks & 3) * 8;
        *(uint2*)(dst + off) = o;
    }
}

// ============================================================================
// conv_wq_fp8: wq_b f32 -> fp8 B-frag, MX layout [ng][kq 12][lane][32B]
// ============================================================================
__global__ __launch_bounds__(256)
void conv_wq_fp8(const float* __restrict__ wq, unsigned char* __restrict__ dst) {
    __shared__ float lds[32][258];
    const int tid = threadIdx.x;
    const int kt = blockIdx.x >> 5, nt = blockIdx.x & 31;
    const int k0 = kt * 32, n0 = nt * 256;
#pragma unroll
    for (int it = 0; it < 8; ++it) {
        int fid = it * 256 + tid;
        int k = fid >> 6, c4 = (fid & 63) << 2;
        float4 v = *(const float4*)(wq + (size_t)(k0 + k) * QN + n0 + c4);
        lds[k][c4] = v.x; lds[k][c4 + 1] = v.y; lds[k][c4 + 2] = v.z; lds[k][c4 + 3] = v.w;
    }
    __syncthreads();
    const int lane = tid & 63, wid = tid >> 6;
#pragma unroll
    for (int j = 0; j < 4; ++j) {
        int s = wid * 4 + j;
        int n_l = s * 16 + (lane & 15);
        int kb = (lane >> 4) << 3;
        uint2 o;
        o.x = pk4fp8(lds[kb][n_l], lds[kb + 1][n_l], lds[kb + 2][n_l], lds[kb + 3][n_l]);
        o.y = pk4fp8(lds[kb + 4][n_l], lds[kb + 5][n_l], lds[kb + 6][n_l], lds[kb + 7][n_l]);
        size_t ng = (size_t)nt * 16 + s;
        size_t off = ((ng * 12 + (kt >> 2)) * 64 + lane) * 32 + (kt & 3) * 8;
        *(uint2*)(dst + off) = o;
    }
}

// ============================================================================
// conv_wkw
// ============================================================================
__global__ __launch_bounds__(256)
void conv_wkw(const float* __restrict__ wk, const float* __restrict__ wp,
              unsigned short* __restrict__ dst) {
    int gid = blockIdx.x * 4 + (threadIdx.x >> 6);
    int lane = threadIdx.x & 63;
    int ng = gid / 224, ks = gid - ng * 224;
    int col = ng * 16 + (lane & 15);
    int k = ks * 32 + ((lane >> 4) << 3);
    unsigned short o[8];
#pragma unroll
    for (int e = 0; e < 8; ++e) {
        float v = (col < 128) ? wk[(size_t)(k + e) * 128 + col]
                              : wp[(size_t)(k + e) * 64 + (col - 128)];
        o[e] = f2bf(v);
    }
    *(short8*)(dst + ((size_t)gid * 64 + lane) * 8) = *(short8*)o;
}

// ============================================================================
// kw_gemm_mfma v2 (verified round 13)
// ============================================================================
__global__ __launch_bounds__(256, 4)
void kw_gemm_mfma(const unsigned short* __restrict__ hsfrag,
                  const unsigned short* __restrict__ wkwfrag,
                  float* __restrict__ part) {
    const int kz = blockIdx.x >> 8;              // 0..3
    const int ig = blockIdx.x & 255;             // 0..255
    const int lane = threadIdx.x & 63, wid = threadIdx.x >> 6;
    const f32x4 zed = {0.f, 0.f, 0.f, 0.f};
    f32x4 acc[3];
#pragma unroll
    for (int j = 0; j < 3; ++j) acc[j] = zed;

    const unsigned short* ap = hsfrag + ((size_t)ig * 224 * 64 + lane) * 8;
    const unsigned short* bp = wkwfrag + ((size_t)(wid * 3) * 224 * 64 + lane) * 8;
#pragma unroll 4
    for (int ks = kz * 56; ks < kz * 56 + 56; ++ks) {
        short8 a = *(const short8*)(ap + (size_t)ks * 512);
        short8 b0 = *(const short8*)(bp + (size_t)ks * 512);
        short8 b1 = *(const short8*)(bp + (size_t)(224 * 64 * 8) + (size_t)ks * 512);
        short8 b2 = *(const short8*)(bp + (size_t)(2 * 224 * 64 * 8) + (size_t)ks * 512);
        acc[0] = MFMA16(a, b0, acc[0]);
        acc[1] = MFMA16(a, b1, acc[1]);
        acc[2] = MFMA16(a, b2, acc[2]);
    }
    const int colc = lane & 15, rsub = (lane >> 4) << 2;
    float* pb = part + (size_t)kz * T_DIM * 192;
#pragma unroll
    for (int j = 0; j < 3; ++j) {
        int ng = wid * 3 + j;
#pragma unroll
        for (int r = 0; r < 4; ++r) {
            int row = ig * 16 + rsub + r;
            pb[(size_t)row * 192 + ng * 16 + colc] = acc[j][r];
        }
    }
}

// ============================================================================
// reduce_w
// ============================================================================
__global__ __launch_bounds__(256)
void reduce_w(const float* __restrict__ part, float* __restrict__ wT) {
    __shared__ float lds[64][65];
    const int r0 = blockIdx.x * 64;
    const int tid = threadIdx.x;
#pragma unroll
    for (int it = 0; it < 16; ++it) {
        int fid = it * 256 + tid;
        int rl = fid >> 6, h = fid & 63;
        float s = 0.f;
#pragma unroll
        for (int z = 0; z < 4; ++z)
            s += part[((size_t)z * T_DIM + r0 + rl) * 192 + 128 + h];
        lds[rl][h] = s * WSCALE;
    }
    __syncthreads();
#pragma unroll
    for (int it = 0; it < 16; ++it) {
        int fid = it * 256 + tid;
        int h = fid >> 6, rl = fid & 63;
        wT[(size_t)h * T_DIM + r0 + rl] = lds[rl][h];
    }
}

// ============================================================================
// ln_rope_k: reduce + LN + rope; fp8 kfrag layout [jg][lane][32B]
// ============================================================================
__global__ __launch_bounds__(256)
void ln_rope_k(const float* __restrict__ part, const float2* __restrict__ tab,
               const float* __restrict__ gamma, const float* __restrict__ beta,
               unsigned char* __restrict__ kfrag) {
    __shared__ float ln[4][128];
    const int tid = threadIdx.x;
    const int wr = tid >> 6, lane = tid & 63;
    const int row = blockIdx.x * 4 + wr;
    float2 v = make_float2(0.f, 0.f);
#pragma unroll
    for (int z = 0; z < 4; ++z) {
        float2 p = *(const float2*)(part + ((size_t)z * T_DIM + row) * 192 + lane * 2);
        v.x += p.x; v.y += p.y;
    }
    float s = v.x + v.y;
#pragma unroll
    for (int off = 1; off < 64; off <<= 1) s += __shfl_xor(s, off);
    float mu = s * (1.0f / 128.0f);
    float d0 = v.x - mu, d1 = v.y - mu;
    float s2 = d0 * d0 + d1 * d1;
#pragma unroll
    for (int off = 1; off < 64; off <<= 1) s2 += __shfl_xor(s2, off);
    float rstd = 1.0f / sqrtf(s2 * (1.0f / 128.0f) + 1e-6f);
    ln[wr][lane * 2]     = d0 * rstd * gamma[lane * 2]     + beta[lane * 2];
    ln[wr][lane * 2 + 1] = d1 * rstd * gamma[lane * 2 + 1] + beta[lane * 2 + 1];
    __syncthreads();
    int d = lane * 2;
    float o0, o1;
    float v0 = ln[wr][d], v1 = ln[wr][d + 1];
    if (d < 64) {
        int dd = d & 31;
        float2 c0 = tab[(size_t)row * 32 + dd];
        float2 c1 = tab[(size_t)row * 32 + dd + 1];
        if (d < 32) {
            o0 = v0 * c0.x - ln[wr][d + 32] * c0.y;
            o1 = v1 * c1.x - ln[wr][d + 33] * c1.y;
        } else {
            o0 = v0 * c0.x + ln[wr][d - 32] * c0.y;
            o1 = v1 * c1.x + ln[wr][d - 31] * c1.y;
        }
    } else { o0 = v0; o1 = v1; }
    int jg = row >> 4, ks = d >> 5, sub = d & 31;
    int lp = ((sub >> 3) << 4) + (row & 15);
    size_t bidx = ((size_t)jg * 64 + lp) * 32 + ks * 8 + (sub & 7);
    unsigned pk = (unsigned)__builtin_amdgcn_cvt_pk_fp8_f32(o0, o1, 0, false);
    *(unsigned short*)(kfrag + bidx) = (unsigned short)(pk & 0xFFFFu);
}

// ============================================================================
// q_gemm_mfma v4 (verified round 19): MX K=128, minimal operand liveness.
// ============================================================================
__global__ __launch_bounds__(256, 2)
void q_gemm_mfma(const unsigned char* __restrict__ qr8,
                 const unsigned char* __restrict__ wq8,
                 const float2* __restrict__ tab,
                 unsigned char* __restrict__ qfrag) {
    const int hw = blockIdx.x;
    const int orig = (hw & 7) * 256 + (hw >> 3);
    const int head = orig >> 5, mt = orig & 31;
    const int tid = threadIdx.x, lane = tid & 63, wid = tid >> 6;
    const int wm = wid >> 1, wn = wid & 1;
    const f32x4 zed = {0.f, 0.f, 0.f, 0.f};
    f32x4 acc[4][4];
#pragma unroll
    for (int m = 0; m < 4; m++)
#pragma unroll
        for (int n = 0; n < 4; n++) acc[m][n] = zed;

    const int ig0 = mt * 8 + wm * 4;
    const int ng0 = head * 8 + wn * 4;
    const unsigned char* ap = qr8 + ((size_t)ig0 * 12 * 64 + lane) * 32;
    const unsigned char* bp = wq8 + ((size_t)ng0 * 12 * 64 + lane) * 32;
    for (int kq = 0; kq < 12; ++kq) {
        i32x8 a0_ = *(const i32x8*)(ap + (size_t)(0 * 12 + kq) * 2048);
        i32x8 a1_ = *(const i32x8*)(ap + (size_t)(1 * 12 + kq) * 2048);
        i32x8 a2_ = *(const i32x8*)(ap + (size_t)(2 * 12 + kq) * 2048);
        i32x8 a3_ = *(const i32x8*)(ap + (size_t)(3 * 12 + kq) * 2048);
#pragma unroll
        for (int n = 0; n < 4; n++) {
            i32x8 b = *(const i32x8*)(bp + ((size_t)n * 12 + kq) * 2048);
            acc[0][n] = MFMA8S(a0_, b, acc[0][n]);
            acc[1][n] = MFMA8S(a1_, b, acc[1][n]);
            acc[2][n] = MFMA8S(a2_, b, acc[2][n]);
            acc[3][n] = MFMA8S(a3_, b, acc[3][n]);
        }
    }
    const int colc = lane & 15;
    const int rsub = (lane >> 4) << 2;
#pragma unroll
    for (int m = 0; m < 4; m++) {
#pragma unroll
        for (int r = 0; r < 4; r++) {
            int row = mt * 128 + wm * 64 + m * 16 + rsub + r;
            int rl = rsub + r;
            size_t base = ((size_t)(row >> 4) * 64 + head) * 2048;
            if (wn == 0) {
#pragma unroll
                for (int n2 = 0; n2 < 2; n2++) {
                    int dd = n2 * 16 + colc;
                    float2 cs = tab[(size_t)row * 32 + dd];
                    float x1 = acc[m][n2][r], x2 = acc[m][n2 + 2][r];
                    float olo = x1 * cs.x - x2 * cs.y;
                    float ohi = x2 * cs.x + x1 * cs.y;
                    int lp = ((dd >> 3) << 4) + rl;
                    qfrag[base + lp * 32 + 0 * 8 + (dd & 7)] = f2fp8(olo);
                    qfrag[base + lp * 32 + 1 * 8 + (dd & 7)] = f2fp8(ohi);
                }
            } else {
#pragma unroll
                for (int n = 0; n < 4; n++) {
                    int d = 64 + n * 16 + colc;
                    int ks2 = d >> 5, sub = d & 31;
                    int lp = ((sub >> 3) << 4) + rl;
                    qfrag[base + lp * 32 + ks2 * 8 + (sub & 7)] = f2fp8(acc[m][n][r]);
                }
            }
        }
    }
}

// ============================================================================
// scores_mfma v13: v11 (verified 109us, VGPR 100) + HALF-step prefetch:
// 4 named buffers, loop step 4, loads 2 SCOMPs ahead, peak 3 live buffers
// (+8 VGPR nominal). Round-22's 4-deep variant ballooned VGPR 100->168 and
// occupancy 16->9% (156us); this caps liveness to recover occupancy while
// covering ~400cyc of L3 latency. Tail loads read <=4KB past slice (safe).
// ============================================================================
#define SCOMP(A, hh) {                                                         \
    f32x4 s0 = MFMA8S(A, kf8[0], zed);                                         \
    f32x4 s1 = MFMA8S(A, kf8[1], zed);                                         \
    f32x4 s2 = MFMA8S(A, kf8[2], zed);                                         \
    f32x4 s3 = MFMA8S(A, kf8[3], zed);                                         \
    f32x4 s4 = MFMA8S(A, kf8[4], zed);                                         \
    f32x4 s5 = MFMA8S(A, kf8[5], zed);                                         \
    f32x4 s6 = MFMA8S(A, kf8[6], zed);                                         \
    f32x4 s7 = MFMA8S(A, kf8[7], zed);                                         \
    f32x4 wv = *(const f32x4*)&wlds[hh][wid * 16 + rsub];                      \
    _Pragma("unroll")                                                          \
    for (int rr_ = 0; rr_ < 4; ++rr_) {                                        \
        acc[0][rr_] += wv[rr_] * fmaxf(s0[rr_], 0.0f);                         \
        acc[1][rr_] += wv[rr_] * fmaxf(s1[rr_], 0.0f);                         \
        acc[2][rr_] += wv[rr_] * fmaxf(s2[rr_], 0.0f);                         \
        acc[3][rr_] += wv[rr_] * fmaxf(s3[rr_], 0.0f);                         \
        acc[4][rr_] += wv[rr_] * fmaxf(s4[rr_], 0.0f);                         \
        acc[5][rr_] += wv[rr_] * fmaxf(s5[rr_], 0.0f);                         \
        acc[6][rr_] += wv[rr_] * fmaxf(s6[rr_], 0.0f);                         \
        acc[7][rr_] += wv[rr_] * fmaxf(s7[rr_], 0.0f);                         \
    }                                                                          \
}

__global__ __launch_bounds__(256)
void scores_mfma(const unsigned char* __restrict__ qfrag,
                 const unsigned char* __restrict__ kfrag,
                 const float* __restrict__ wT, float* __restrict__ S) {
    const int bid = blockIdx.x;                  // 0..1055
    int u = (int)((sqrtf(4.f * bid + 1.f) - 1.f) * 0.5f);
    while ((u + 1) * (u + 2) <= bid) ++u;
    while (u * (u + 1) > bid) --u;
    int r_ = bid - u * (u + 1);                  // 0..2u+1
    const int byp = (r_ <= u) ? 2 * u : 2 * u + 1;
    const int jt  = (r_ <= u) ? r_ : r_ - (u + 1);
    __shared__ float wlds[64][64];
    const int tid = threadIdx.x;
    const int lane = tid & 63, wid = tid >> 6;   // wave = ig owner (0..3)
    const int i0 = byp * 64, j0 = jt * 128;
    const f32x4 zed = {0.f, 0.f, 0.f, 0.f};
#pragma unroll
    for (int it = 0; it < 16; ++it) {
        int fid = it * 256 + tid;
        int hh = fid >> 6, rl = fid & 63;
        wlds[hh][rl] = wT[(size_t)hh * T_DIM + i0 + rl];
    }
    i32x8 kf8[8];
#pragma unroll
    for (int n = 0; n < 8; ++n) {
        int jg = (j0 >> 4) + n;
        kf8[n] = *(const i32x8*)(kfrag + ((size_t)jg * 64 + lane) * 32);
    }
    __syncthreads();

    f32x4 acc[8];
#pragma unroll
    for (int n = 0; n < 8; n++) acc[n] = zed;

    const int rsub = (lane >> 4) << 2;
    const unsigned char* qb = qfrag + (size_t)(byp * 4 + wid) * 131072 + lane * 32;

    i32x8 a0 = *(const i32x8*)(qb + 0 * 2048);
    i32x8 a1 = *(const i32x8*)(qb + 1 * 2048);
    for (int h = 0; h < NH; h += 4) {
        i32x8 a2 = *(const i32x8*)(qb + (size_t)(h + 2) * 2048);
        SCOMP(a0, h)
        i32x8 a3 = *(const i32x8*)(qb + (size_t)(h + 3) * 2048);
        SCOMP(a1, h + 1)
        a0 = *(const i32x8*)(qb + (size_t)(h + 4) * 2048);
        SCOMP(a2, h + 2)
        a1 = *(const i32x8*)(qb + (size_t)(h + 5) * 2048);
        SCOMP(a3, h + 3)
    }

    const int colc = lane & 15;
#pragma unroll
    for (int n = 0; n < 8; n++) {
        int col = j0 + n * 16 + colc;
#pragma unroll
        for (int rr = 0; rr < 4; rr++) {
            int row = i0 + wid * 16 + rsub + rr;
            float v = acc[n][rr];
            if (col > row) v = MASK_VAL;
            S[(size_t)row * T_DIM + col] = v;
        }
    }
}

// ============================================================================
// topk v7: E=8 keys/thread bitonic (verified round 21)
// ============================================================================
__device__ __forceinline__ void ce(unsigned &x, unsigned &y, bool up) {
    unsigned lo = x < y ? x : y, hi = x < y ? y : x;
    x = up ? lo : hi; y = up ? hi : lo;
}
__device__ __forceinline__ unsigned cd(unsigned a, unsigned b, bool keep_lo) {
    unsigned lo = a < b ? a : b, hi = a < b ? b : a;
    return keep_lo ? lo : hi;
}

#define CE8S(k, j) {                                                           \
    const bool kl_ = ((e0 & (k)) == 0u) ^ ((e0 & (j)) != 0u);                  \
    q0 = cd(q0, (unsigned)__shfl_xor((int)q0, (j) >> 3), kl_);                 \
    q1 = cd(q1, (unsigned)__shfl_xor((int)q1, (j) >> 3), kl_);                 \
    q2 = cd(q2, (unsigned)__shfl_xor((int)q2, (j) >> 3), kl_);                 \
    q3 = cd(q3, (unsigned)__shfl_xor((int)q3, (j) >> 3), kl_);                 \
    q4 = cd(q4, (unsigned)__shfl_xor((int)q4, (j) >> 3), kl_);                 \
    q5 = cd(q5, (unsigned)__shfl_xor((int)q5, (j) >> 3), kl_);                 \
    q6 = cd(q6, (unsigned)__shfl_xor((int)q6, (j) >> 3), kl_);                 \
    q7 = cd(q7, (unsigned)__shfl_xor((int)q7, (j) >> 3), kl_); }

#define CE8R(k) {                                                              \
    const bool up_ = ((e0 & (k)) == 0u);                                       \
    ce(q0, q4, up_); ce(q1, q5, up_); ce(q2, q6, up_); ce(q3, q7, up_);        \
    ce(q0, q2, up_); ce(q1, q3, up_); ce(q4, q6, up_); ce(q5, q7, up_);        \
    ce(q0, q1, up_); ce(q2, q3, up_); ce(q4, q5, up_); ce(q6, q7, up_); }

#define CE8L(k, j) {                                                           \
    __syncthreads();                                                           \
    *(uint4*)&L[e0]     = make_uint4(q0, q1, q2, q3);                          \
    *(uint4*)&L[e0 + 4] = make_uint4(q4, q5, q6, q7);                          \
    __syncthreads();                                                           \
    uint4 pA_ = *(uint4*)&L[(e0 ^ (j))];                                       \
    uint4 pB_ = *(uint4*)&L[(e0 ^ (j)) + 4];                                   \
    const bool kl_ = ((e0 & (k)) == 0u) ^ ((e0 & (j)) != 0u);                  \
    q0 = cd(q0, pA_.x, kl_); q1 = cd(q1, pA_.y, kl_);                          \
    q2 = cd(q2, pA_.z, kl_); q3 = cd(q3, pA_.w, kl_);                          \
    q4 = cd(q4, pB_.x, kl_); q5 = cd(q5, pB_.y, kl_);                          \
    q6 = cd(q6, pB_.z, kl_); q7 = cd(q7, pB_.w, kl_); }

#define CM8L(j) {                                                              \
    __syncthreads();                                                           \
    if (low) {                                                                 \
        *(uint4*)&L[e0]     = make_uint4(q0, q1, q2, q3);                      \
        *(uint4*)&L[e0 + 4] = make_uint4(q4, q5, q6, q7);                      \
    }                                                                          \
    __syncthreads();                                                           \
    if (low) {                                                                 \
        uint4 pA_ = *(uint4*)&L[(e0 ^ (j))];                                   \
        uint4 pB_ = *(uint4*)&L[(e0 ^ (j)) + 4];                               \
        const bool kl_ = (e0 & (j)) == 0u;                                     \
        q0 = cd(q0, pA_.x, kl_); q1 = cd(q1, pA_.y, kl_);                      \
        q2 = cd(q2, pA_.z, kl_); q3 = cd(q3, pA_.w, kl_);                      \
        q4 = cd(q4, pB_.x, kl_); q5 = cd(q5, pB_.y, kl_);                      \
        q6 = cd(q6, pB_.z, kl_); q7 = cd(q7, pB_.w, kl_); } }

#define CM8S(j) {                                                              \
    const bool kl_ = (e0 & (j)) == 0u;                                         \
    q0 = cd(q0, (unsigned)__shfl_xor((int)q0, (j) >> 3), kl_);                 \
    q1 = cd(q1, (unsigned)__shfl_xor((int)q1, (j) >> 3), kl_);                 \
    q2 = cd(q2, (unsigned)__shfl_xor((int)q2, (j) >> 3), kl_);                 \
    q3 = cd(q3, (unsigned)__shfl_xor((int)q3, (j) >> 3), kl_);                 \
    q4 = cd(q4, (unsigned)__shfl_xor((int)q4, (j) >> 3), kl_);                 \
    q5 = cd(q5, (unsigned)__shfl_xor((int)q5, (j) >> 3), kl_);                 \
    q6 = cd(q6, (unsigned)__shfl_xor((int)q6, (j) >> 3), kl_);                 \
    q7 = cd(q7, (unsigned)__shfl_xor((int)q7, (j) >> 3), kl_); }

__global__ __launch_bounds__(1024)
void topk_kernel(const float* __restrict__ S, float* __restrict__ outIdx) {
    __shared__ unsigned lds[8192];
    const int bid = blockIdx.x;
    const int tid = threadIdx.x;

    int row; unsigned e0; unsigned* L; bool longrow;
    if (bid < 512) {             // 4 short rows (row < 2048), 256 thr each
        int slot = tid >> 8;
        row = bid * 4 + slot;
        e0 = 8u * (tid & 255);
        L = &lds[slot * 2048];
        longrow = false;
    } else {                     // 2 long rows, 512 thr each
        int slot = tid >> 9;
        row = 2048 + (bid - 512) * 2 + slot;
        e0 = 8u * (tid & 511);
        L = &lds[slot * 4096];
        longrow = true;
    }

    unsigned q0, q1, q2, q3, q4, q5, q6, q7;
    {   // load 8 keys + mask synth
        float4 f0 = *(const float4*)(S + (size_t)row * T_DIM + e0);
        float4 f1 = *(const float4*)(S + (size_t)row * T_DIM + e0 + 4);
        const float fp[8] = {f0.x, f0.y, f0.z, f0.w, f1.x, f1.y, f1.z, f1.w};
        unsigned qq[8];
#pragma unroll
        for (int e = 0; e < 8; ++e) {
            unsigned p = e0 + e;
            unsigned u = __float_as_uint(fp[e]);
            u = (u & 0x80000000u) ? ~u : (u | 0x80000000u);
            unsigned key = ((~u) & 0xFFFFF000u) | p;
            qq[e] = ((int)p > row) ? (0xFFFFF000u | p) : key;
        }
        q0 = qq[0]; q1 = qq[1]; q2 = qq[2]; q3 = qq[3];
        q4 = qq[4]; q5 = qq[5]; q6 = qq[6]; q7 = qq[7];
    }
    // in-thread stages k=2,4,8 (directions from global index bits)
    ce(q0, q1, true);  ce(q2, q3, false); ce(q4, q5, true);  ce(q6, q7, false);
    ce(q0, q2, true);  ce(q1, q3, true);  ce(q4, q6, false); ce(q5, q7, false);
    ce(q0, q1, true);  ce(q2, q3, true);  ce(q4, q5, false); ce(q6, q7, false);
    {
        const bool up8 = ((e0 & 8u) == 0u);
        ce(q0, q4, up8); ce(q1, q5, up8); ce(q2, q6, up8); ce(q3, q7, up8);
        ce(q0, q2, up8); ce(q1, q3, up8); ce(q4, q6, up8); ce(q5, q7, up8);
        ce(q0, q1, up8); ce(q2, q3, up8); ce(q4, q5, up8); ce(q6, q7, up8);
    }
    // stages k=16..2048
    CE8S(16u, 8u)                                                CE8R(16u)
    CE8S(32u, 16u)  CE8S(32u, 8u)                                CE8R(32u)
    CE8S(64u, 32u)  CE8S(64u, 16u)  CE8S(64u, 8u)                CE8R(64u)
    CE8S(128u, 64u) CE8S(128u, 32u) CE8S(128u, 16u) CE8S(128u, 8u) CE8R(128u)
    CE8S(256u, 128u) CE8S(256u, 64u) CE8S(256u, 32u)
    CE8S(256u, 16u)  CE8S(256u, 8u)                              CE8R(256u)
    CE8S(512u, 256u) CE8S(512u, 128u) CE8S(512u, 64u)
    CE8S(512u, 32u)  CE8S(512u, 16u)  CE8S(512u, 8u)             CE8R(512u)
    CE8L(1024u, 512u)
    CE8S(1024u, 256u) CE8S(1024u, 128u) CE8S(1024u, 64u)
    CE8S(1024u, 32u)  CE8S(1024u, 16u)  CE8S(1024u, 8u)          CE8R(1024u)
    CE8L(2048u, 1024u) CE8L(2048u, 512u)
    CE8S(2048u, 256u) CE8S(2048u, 128u) CE8S(2048u, 64u)
    CE8S(2048u, 32u)  CE8S(2048u, 16u)  CE8S(2048u, 8u)          CE8R(2048u)

    if (!longrow) {
        float4 o0 = make_float4((float)(q0 & 0xFFFu), (float)(q1 & 0xFFFu),
                                (float)(q2 & 0xFFFu), (float)(q3 & 0xFFFu));
        float4 o1 = make_float4((float)(q4 & 0xFFFu), (float)(q5 & 0xFFFu),
                                (float)(q6 & 0xFFFu), (float)(q7 & 0xFFFu));
        *(float4*)(outIdx + (size_t)row * TOPK_N + e0) = o0;
        *(float4*)(outIdx + (size_t)row * TOPK_N + e0 + 4) = o1;
    } else {
        // merge k=4096: mins into lower 2048, then ascending clean of lower.
        __syncthreads();
        *(uint4*)&L[e0]     = make_uint4(q0, q1, q2, q3);
        *(uint4*)&L[e0 + 4] = make_uint4(q4, q5, q6, q7);
        __syncthreads();
        const bool low = e0 < 2048u;
        if (low) {
            uint4 pA = *(uint4*)&L[e0 + 2048];
            uint4 pB = *(uint4*)&L[e0 + 2048 + 4];
            q0 = q0 < pA.x ? q0 : pA.x; q1 = q1 < pA.y ? q1 : pA.y;
            q2 = q2 < pA.z ? q2 : pA.z; q3 = q3 < pA.w ? q3 : pA.w;
            q4 = q4 < pB.x ? q4 : pB.x; q5 = q5 < pB.y ? q5 : pB.y;
            q6 = q6 < pB.z ? q6 : pB.z; q7 = q7 < pB.w ? q7 : pB.w;
        }
        CM8L(1024u) CM8L(512u)
        if (low) {
            CM8S(256u) CM8S(128u) CM8S(64u) CM8S(32u) CM8S(16u) CM8S(8u)
            ce(q0, q4, true); ce(q1, q5, true); ce(q2, q6, true); ce(q3, q7, true);
            ce(q0, q2, true); ce(q1, q3, true); ce(q4, q6, true); ce(q5, q7, true);
            ce(q0, q1, true); ce(q2, q3, true); ce(q4, q5, true); ce(q6, q7, true);
            float4 o0 = make_float4((float)(q0 & 0xFFFu), (float)(q1 & 0xFFFu),
                                    (float)(q2 & 0xFFFu), (float)(q3 & 0xFFFu));
            float4 o1 = make_float4((float)(q4 & 0xFFFu), (float)(q5 & 0xFFFu),
                                    (float)(q6 & 0xFFFu), (float)(q7 & 0xFFFu));
            *(float4*)(outIdx + (size_t)row * TOPK_N + e0) = o0;
            *(float4*)(outIdx + (size_t)row * TOPK_N + e0 + 4) = o1;
        }
    }
}

// ============================================================================
extern "C" void kernel_launch(void* const* d_in, const int* in_sizes, int n_in,
                              void* d_out, int out_size, void* d_ws, size_t ws_size,
                              hipStream_t stream) {
    const float* hs      = (const float*)d_in[0];
    const float* qr      = (const float*)d_in[1];
    const int*   pos     = (const int*)  d_in[2];
    const float* wq_b    = (const float*)d_in[3];
    const float* wk      = (const float*)d_in[4];
    const float* k_gamma = (const float*)d_in[5];
    const float* k_beta  = (const float*)d_in[6];
    const float* w_proj  = (const float*)d_in[7];

    float* out     = (float*)d_out;
    float* out_idx = out;
    float* S       = out + (size_t)T_DIM * TOPK_N;

    char* wsp = (char*)d_ws;
    unsigned char*  qfrag  = (unsigned char*)wsp;  wsp += (size_t)67108864;
    unsigned short* hsfrag = (unsigned short*)qfrag;  // alias: hs consumed before qfrag written
    unsigned char*  qrfrag = (unsigned char*)wsp;  wsp += (size_t)12582912;
    unsigned char*  wqfrag = (unsigned char*)wsp;  wsp += (size_t)25165824;
    unsigned short* wkwfrag= (unsigned short*)wsp; wsp += (size_t)2752512;
    float*          part   = (float*)wsp;          wsp += (size_t)12582912;
    float*          wT     = (float*)wsp;          wsp += (size_t)1048576;
    unsigned char*  kfrag  = (unsigned char*)wsp;  wsp += (size_t)1048576;
    float2*         tab    = (float2*)wsp;         wsp += (size_t)1048576;

    rope_tab_kernel<<<512, 256, 0, stream>>>(pos, tab);
    conv_afrag <<<3584, 256, 0, stream>>>(hs, hsfrag, HSZ, 224, 28);
    conv_wkw   <<<672,  256, 0, stream>>>(wk, w_proj, wkwfrag);
    kw_gemm_mfma<<<1024, 256, 0, stream>>>(hsfrag, wkwfrag, part);
    reduce_w   <<<64,   256, 0, stream>>>(part, wT);
    ln_rope_k  <<<T_DIM / 4, 256, 0, stream>>>(part, tab, k_gamma, k_beta, kfrag);
    conv_qr_fp8<<<768,  256, 0, stream>>>(qr, qrfrag);
    conv_wq_fp8<<<1536, 256, 0, stream>>>(wq_b, wqfrag);
    q_gemm_mfma<<<2048, 256, 0, stream>>>(qrfrag, wqfrag, tab, qfrag);
    scores_mfma<<<1056, 256, 0, stream>>>(qfrag, kfrag, wT, S);
    topk_kernel<<<1536, 1024, 0, stream>>>(S, out_idx);
}

// Round 24
// 391.559 us; speedup vs baseline: 1.1227x; 1.1209x over previous
//
#include <hip/hip_runtime.h>
#include <hip/hip_bf16.h>
#include <math.h>

#define T_DIM 4096
#define HSZ   7168
#define QLR_K 1536
#define NH    64
#define HD    128
#define QN    (NH*HD)   // 8192
#define TOPK_N 2048
#define MASK_VAL (-3.0e38f)
// 0.125 (w_proj scale) * 128^-0.5 (q scale, folded out of fp8 q for precision)
#define WSCALE 0.011048543456039806f

using short8 = __attribute__((ext_vector_type(8))) short;   // 8 bf16 (4 VGPR)
using f32x4  = __attribute__((ext_vector_type(4))) float;
using i32x8  = __attribute__((ext_vector_type(8))) int;     // fp8 x32 (8 VGPR)

#define MFMA16(a,b,c) __builtin_amdgcn_mfma_f32_16x16x32_bf16(a,b,c,0,0,0)
#define MFMA8(a,b,c)  __builtin_amdgcn_mfma_f32_16x16x32_fp8_fp8(a,b,c,0,0,0)
// MX-scaled K=128 fp8: fmt 0/0 = e4m3/e4m3, scale byte 127 = 2^0 = 1.0.
#define MFMA8S(a,b,c) __builtin_amdgcn_mfma_scale_f32_16x16x128_f8f6f4(a,b,c,0,0,0,127,0,127)

__device__ __forceinline__ float rope_invf(int d) {
    return (float)(1.0 / pow(10000.0, (double)d / 32.0));
}
__device__ __forceinline__ unsigned short f2bf(float f) {
    unsigned u = __float_as_uint(f);
    return (unsigned short)((u + 0x7FFFu + ((u >> 16) & 1u)) >> 16);
}
// HW fp8 e4m3 conversion (v_cvt_pk_fp8_f32, gfx940+)
__device__ __forceinline__ unsigned char f2fp8(float x) {
    return (unsigned char)(__builtin_amdgcn_cvt_pk_fp8_f32(x, x, 0, false) & 0xFF);
}
__device__ __forceinline__ unsigned pk4fp8(float a, float b, float c, float d) {
    unsigned w = (unsigned)__builtin_amdgcn_cvt_pk_fp8_f32(a, b, 0, false);
    return (unsigned)__builtin_amdgcn_cvt_pk_fp8_f32(c, d, (int)w, true);
}

// ============================================================================
// rope_tab
// ============================================================================
__global__ __launch_bounds__(256)
void rope_tab_kernel(const int* __restrict__ positions, float2* __restrict__ tab) {
    int idx = blockIdx.x * 256 + threadIdx.x;
    int t = idx >> 5, dd = idx & 31;
    float p = (float)positions[t];
    float ang = p * rope_invf(dd);
    float s, c; sincosf(ang, &s, &c);
    tab[idx] = make_float2(c, s);
}

// ============================================================================
// conv_afrag (bf16, for hs -> kw path)
// ============================================================================
__global__ __launch_bounds__(256)
void conv_afrag(const float* __restrict__ src, unsigned short* __restrict__ dst,
                int C, int KS, int ctiles) {
    __shared__ float lds[32][258];
    const int tid = threadIdx.x;
    const int rt = blockIdx.x / ctiles, ct = blockIdx.x - rt * ctiles;
    const int r0 = rt * 32, c0 = ct * 256;
#pragma unroll
    for (int it = 0; it < 8; ++it) {
        int fid = it * 256 + tid;
        int r = fid >> 6, c4 = (fid & 63) << 2;
        float4 v = *(const float4*)(src + (size_t)(r0 + r) * C + c0 + c4);
        lds[r][c4] = v.x; lds[r][c4 + 1] = v.y; lds[r][c4 + 2] = v.z; lds[r][c4 + 3] = v.w;
    }
    __syncthreads();
    const int lane = tid & 63, wid = tid >> 6;
#pragma unroll
    for (int j = 0; j < 4; ++j) {
        int s = wid * 4 + j;
        int ig_l = s >> 3, ks_l = s & 7;
        int r = ig_l * 16 + (lane & 15);
        int c = ks_l * 32 + ((lane >> 4) << 3);
        unsigned short o[8];
#pragma unroll
        for (int e = 0; e < 8; ++e) o[e] = f2bf(lds[r][c + e]);
        size_t ig = rt * 2 + ig_l, ks = (size_t)ct * 8 + ks_l;
        *(short8*)(dst + ((ig * KS + ks) * 64 + lane) * 8) = *(short8*)o;
    }
}

// ============================================================================
// conv_qr_fp8: qr f32 -> fp8 A-frag, MX layout [ig][kq 12][lane][32B]
// ============================================================================
__global__ __launch_bounds__(256)
void conv_qr_fp8(const float* __restrict__ src, unsigned char* __restrict__ dst) {
    __shared__ float lds[32][258];
    const int tid = threadIdx.x;
    const int rt = blockIdx.x / 6, ct = blockIdx.x - rt * 6;
    const int r0 = rt * 32, c0 = ct * 256;
#pragma unroll
    for (int it = 0; it < 8; ++it) {
        int fid = it * 256 + tid;
        int r = fid >> 6, c4 = (fid & 63) << 2;
        float4 v = *(const float4*)(src + (size_t)(r0 + r) * QLR_K + c0 + c4);
        lds[r][c4] = v.x; lds[r][c4 + 1] = v.y; lds[r][c4 + 2] = v.z; lds[r][c4 + 3] = v.w;
    }
    __syncthreads();
    const int lane = tid & 63, wid = tid >> 6;
#pragma unroll
    for (int j = 0; j < 4; ++j) {
        int s = wid * 4 + j;
        int ig_l = s >> 3, ks_l = s & 7;
        int r = ig_l * 16 + (lane & 15);
        int c = ks_l * 32 + ((lane >> 4) << 3);
        uint2 o;
        o.x = pk4fp8(lds[r][c], lds[r][c + 1], lds[r][c + 2], lds[r][c + 3]);
        o.y = pk4fp8(lds[r][c + 4], lds[r][c + 5], lds[r][c + 6], lds[r][c + 7]);
        size_t ig = rt * 2 + ig_l;
        int ks = ct * 8 + ks_l;
        size_t off = ((ig * 12 + (ks >> 2)) * 64 + lane) * 32 + (ks & 3) * 8;
        *(uint2*)(dst + off) = o;
    }
}

// ============================================================================
// conv_wq_fp8: wq_b f32 -> fp8 B-frag, MX layout [ng][kq 12][lane][32B]
// ============================================================================
__global__ __launch_bounds__(256)
void conv_wq_fp8(const float* __restrict__ wq, unsigned char* __restrict__ dst) {
    __shared__ float lds[32][258];
    const int tid = threadIdx.x;
    const int kt = blockIdx.x >> 5, nt = blockIdx.x & 31;
    const int k0 = kt * 32, n0 = nt * 256;
#pragma unroll
    for (int it = 0; it < 8; ++it) {
        int fid = it * 256 + tid;
        int k = fid >> 6, c4 = (fid & 63) << 2;
        float4 v = *(const float4*)(wq + (size_t)(k0 + k) * QN + n0 + c4);
        lds[k][c4] = v.x; lds[k][c4 + 1] = v.y; lds[k][c4 + 2] = v.z; lds[k][c4 + 3] = v.w;
    }
    __syncthreads();
    const int lane = tid & 63, wid = tid >> 6;
#pragma unroll
    for (int j = 0; j < 4; ++j) {
        int s = wid * 4 + j;
        int n_l = s * 16 + (lane & 15);
        int kb = (lane >> 4) << 3;
        uint2 o;
        o.x = pk4fp8(lds[kb][n_l], lds[kb + 1][n_l], lds[kb + 2][n_l], lds[kb + 3][n_l]);
        o.y = pk4fp8(lds[kb + 4][n_l], lds[kb + 5][n_l], lds[kb + 6][n_l], lds[kb + 7][n_l]);
        size_t ng = (size_t)nt * 16 + s;
        size_t off = ((ng * 12 + (kt >> 2)) * 64 + lane) * 32 + (kt & 3) * 8;
        *(uint2*)(dst + off) = o;
    }
}

// ============================================================================
// conv_wkw
// ============================================================================
__global__ __launch_bounds__(256)
void conv_wkw(const float* __restrict__ wk, const float* __restrict__ wp,
              unsigned short* __restrict__ dst) {
    int gid = blockIdx.x * 4 + (threadIdx.x >> 6);
    int lane = threadIdx.x & 63;
    int ng = gid / 224, ks = gid - ng * 224;
    int col = ng * 16 + (lane & 15);
    int k = ks * 32 + ((lane >> 4) << 3);
    unsigned short o[8];
#pragma unroll
    for (int e = 0; e < 8; ++e) {
        float v = (col < 128) ? wk[(size_t)(k + e) * 128 + col]
                              : wp[(size_t)(k + e) * 64 + (col - 128)];
        o[e] = f2bf(v);
    }
    *(short8*)(dst + ((size_t)gid * 64 + lane) * 8) = *(short8*)o;
}

// ============================================================================
// kw_gemm_mfma v2 (verified round 13)
// ============================================================================
__global__ __launch_bounds__(256, 4)
void kw_gemm_mfma(const unsigned short* __restrict__ hsfrag,
                  const unsigned short* __restrict__ wkwfrag,
                  float* __restrict__ part) {
    const int kz = blockIdx.x >> 8;              // 0..3
    const int ig = blockIdx.x & 255;             // 0..255
    const int lane = threadIdx.x & 63, wid = threadIdx.x >> 6;
    const f32x4 zed = {0.f, 0.f, 0.f, 0.f};
    f32x4 acc[3];
#pragma unroll
    for (int j = 0; j < 3; ++j) acc[j] = zed;

    const unsigned short* ap = hsfrag + ((size_t)ig * 224 * 64 + lane) * 8;
    const unsigned short* bp = wkwfrag + ((size_t)(wid * 3) * 224 * 64 + lane) * 8;
#pragma unroll 4
    for (int ks = kz * 56; ks < kz * 56 + 56; ++ks) {
        short8 a = *(const short8*)(ap + (size_t)ks * 512);
        short8 b0 = *(const short8*)(bp + (size_t)ks * 512);
        short8 b1 = *(const short8*)(bp + (size_t)(224 * 64 * 8) + (size_t)ks * 512);
        short8 b2 = *(const short8*)(bp + (size_t)(2 * 224 * 64 * 8) + (size_t)ks * 512);
        acc[0] = MFMA16(a, b0, acc[0]);
        acc[1] = MFMA16(a, b1, acc[1]);
        acc[2] = MFMA16(a, b2, acc[2]);
    }
    const int colc = lane & 15, rsub = (lane >> 4) << 2;
    float* pb = part + (size_t)kz * T_DIM * 192;
#pragma unroll
    for (int j = 0; j < 3; ++j) {
        int ng = wid * 3 + j;
#pragma unroll
        for (int r = 0; r < 4; ++r) {
            int row = ig * 16 + rsub + r;
            pb[(size_t)row * 192 + ng * 16 + colc] = acc[j][r];
        }
    }
}

// ============================================================================
// reduce_w
// ============================================================================
__global__ __launch_bounds__(256)
void reduce_w(const float* __restrict__ part, float* __restrict__ wT) {
    __shared__ float lds[64][65];
    const int r0 = blockIdx.x * 64;
    const int tid = threadIdx.x;
#pragma unroll
    for (int it = 0; it < 16; ++it) {
        int fid = it * 256 + tid;
        int rl = fid >> 6, h = fid & 63;
        float s = 0.f;
#pragma unroll
        for (int z = 0; z < 4; ++z)
            s += part[((size_t)z * T_DIM + r0 + rl) * 192 + 128 + h];
        lds[rl][h] = s * WSCALE;
    }
    __syncthreads();
#pragma unroll
    for (int it = 0; it < 16; ++it) {
        int fid = it * 256 + tid;
        int h = fid >> 6, rl = fid & 63;
        wT[(size_t)h * T_DIM + r0 + rl] = lds[rl][h];
    }
}

// ============================================================================
// ln_rope_k: reduce + LN + rope; fp8 kfrag layout [jg][lane][32B]
// ============================================================================
__global__ __launch_bounds__(256)
void ln_rope_k(const float* __restrict__ part, const float2* __restrict__ tab,
               const float* __restrict__ gamma, const float* __restrict__ beta,
               unsigned char* __restrict__ kfrag) {
    __shared__ float ln[4][128];
    const int tid = threadIdx.x;
    const int wr = tid >> 6, lane = tid & 63;
    const int row = blockIdx.x * 4 + wr;
    float2 v = make_float2(0.f, 0.f);
#pragma unroll
    for (int z = 0; z < 4; ++z) {
        float2 p = *(const float2*)(part + ((size_t)z * T_DIM + row) * 192 + lane * 2);
        v.x += p.x; v.y += p.y;
    }
    float s = v.x + v.y;
#pragma unroll
    for (int off = 1; off < 64; off <<= 1) s += __shfl_xor(s, off);
    float mu = s * (1.0f / 128.0f);
    float d0 = v.x - mu, d1 = v.y - mu;
    float s2 = d0 * d0 + d1 * d1;
#pragma unroll
    for (int off = 1; off < 64; off <<= 1) s2 += __shfl_xor(s2, off);
    float rstd = 1.0f / sqrtf(s2 * (1.0f / 128.0f) + 1e-6f);
    ln[wr][lane * 2]     = d0 * rstd * gamma[lane * 2]     + beta[lane * 2];
    ln[wr][lane * 2 + 1] = d1 * rstd * gamma[lane * 2 + 1] + beta[lane * 2 + 1];
    __syncthreads();
    int d = lane * 2;
    float o0, o1;
    float v0 = ln[wr][d], v1 = ln[wr][d + 1];
    if (d < 64) {
        int dd = d & 31;
        float2 c0 = tab[(size_t)row * 32 + dd];
        float2 c1 = tab[(size_t)row * 32 + dd + 1];
        if (d < 32) {
            o0 = v0 * c0.x - ln[wr][d + 32] * c0.y;
            o1 = v1 * c1.x - ln[wr][d + 33] * c1.y;
        } else {
            o0 = v0 * c0.x + ln[wr][d - 32] * c0.y;
            o1 = v1 * c1.x + ln[wr][d - 31] * c1.y;
        }
    } else { o0 = v0; o1 = v1; }
    int jg = row >> 4, ks = d >> 5, sub = d & 31;
    int lp = ((sub >> 3) << 4) + (row & 15);
    size_t bidx = ((size_t)jg * 64 + lp) * 32 + ks * 8 + (sub & 7);
    unsigned pk = (unsigned)__builtin_amdgcn_cvt_pk_fp8_f32(o0, o1, 0, false);
    *(unsigned short*)(kfrag + bidx) = (unsigned short)(pk & 0xFFFFu);
}

// ============================================================================
// q_gemm_mfma v4 (verified round 19): MX K=128, minimal operand liveness.
// ============================================================================
__global__ __launch_bounds__(256, 2)
void q_gemm_mfma(const unsigned char* __restrict__ qr8,
                 const unsigned char* __restrict__ wq8,
                 const float2* __restrict__ tab,
                 unsigned char* __restrict__ qfrag) {
    const int hw = blockIdx.x;
    const int orig = (hw & 7) * 256 + (hw >> 3);
    const int head = orig >> 5, mt = orig & 31;
    const int tid = threadIdx.x, lane = tid & 63, wid = tid >> 6;
    const int wm = wid >> 1, wn = wid & 1;
    const f32x4 zed = {0.f, 0.f, 0.f, 0.f};
    f32x4 acc[4][4];
#pragma unroll
    for (int m = 0; m < 4; m++)
#pragma unroll
        for (int n = 0; n < 4; n++) acc[m][n] = zed;

    const int ig0 = mt * 8 + wm * 4;
    const int ng0 = head * 8 + wn * 4;
    const unsigned char* ap = qr8 + ((size_t)ig0 * 12 * 64 + lane) * 32;
    const unsigned char* bp = wq8 + ((size_t)ng0 * 12 * 64 + lane) * 32;
    for (int kq = 0; kq < 12; ++kq) {
        i32x8 a0_ = *(const i32x8*)(ap + (size_t)(0 * 12 + kq) * 2048);
        i32x8 a1_ = *(const i32x8*)(ap + (size_t)(1 * 12 + kq) * 2048);
        i32x8 a2_ = *(const i32x8*)(ap + (size_t)(2 * 12 + kq) * 2048);
        i32x8 a3_ = *(const i32x8*)(ap + (size_t)(3 * 12 + kq) * 2048);
#pragma unroll
        for (int n = 0; n < 4; n++) {
            i32x8 b = *(const i32x8*)(bp + ((size_t)n * 12 + kq) * 2048);
            acc[0][n] = MFMA8S(a0_, b, acc[0][n]);
            acc[1][n] = MFMA8S(a1_, b, acc[1][n]);
            acc[2][n] = MFMA8S(a2_, b, acc[2][n]);
            acc[3][n] = MFMA8S(a3_, b, acc[3][n]);
        }
    }
    const int colc = lane & 15;
    const int rsub = (lane >> 4) << 2;
#pragma unroll
    for (int m = 0; m < 4; m++) {
#pragma unroll
        for (int r = 0; r < 4; r++) {
            int row = mt * 128 + wm * 64 + m * 16 + rsub + r;
            int rl = rsub + r;
            size_t base = ((size_t)(row >> 4) * 64 + head) * 2048;
            if (wn == 0) {
#pragma unroll
                for (int n2 = 0; n2 < 2; n2++) {
                    int dd = n2 * 16 + colc;
                    float2 cs = tab[(size_t)row * 32 + dd];
                    float x1 = acc[m][n2][r], x2 = acc[m][n2 + 2][r];
                    float olo = x1 * cs.x - x2 * cs.y;
                    float ohi = x2 * cs.x + x1 * cs.y;
                    int lp = ((dd >> 3) << 4) + rl;
                    qfrag[base + lp * 32 + 0 * 8 + (dd & 7)] = f2fp8(olo);
                    qfrag[base + lp * 32 + 1 * 8 + (dd & 7)] = f2fp8(ohi);
                }
            } else {
#pragma unroll
                for (int n = 0; n < 4; n++) {
                    int d = 64 + n * 16 + colc;
                    int ks2 = d >> 5, sub = d & 31;
                    int lp = ((sub >> 3) << 4) + rl;
                    qfrag[base + lp * 32 + ks2 * 8 + (sub & 7)] = f2fp8(acc[m][n][r]);
                }
            }
        }
    }
}

// ============================================================================
// scores_mfma v11 (verified round 20: 109us, VGPR 100): wave-per-ig, unique
// Q per wave, 1-ahead double buffer. Rounds 22/23 proved deeper prefetch
// always allocates 168 VGPR (occupancy 16->9%) regardless of source staging
// -- this is the compiler's allocation basin; v11 is the structural optimum.
// ============================================================================
#define SCOMP(A, hh) {                                                         \
    f32x4 s0 = MFMA8S(A, kf8[0], zed);                                         \
    f32x4 s1 = MFMA8S(A, kf8[1], zed);                                         \
    f32x4 s2 = MFMA8S(A, kf8[2], zed);                                         \
    f32x4 s3 = MFMA8S(A, kf8[3], zed);                                         \
    f32x4 s4 = MFMA8S(A, kf8[4], zed);                                         \
    f32x4 s5 = MFMA8S(A, kf8[5], zed);                                         \
    f32x4 s6 = MFMA8S(A, kf8[6], zed);                                         \
    f32x4 s7 = MFMA8S(A, kf8[7], zed);                                         \
    f32x4 wv = *(const f32x4*)&wlds[hh][wid * 16 + rsub];                      \
    _Pragma("unroll")                                                          \
    for (int rr_ = 0; rr_ < 4; ++rr_) {                                        \
        acc[0][rr_] += wv[rr_] * fmaxf(s0[rr_], 0.0f);                         \
        acc[1][rr_] += wv[rr_] * fmaxf(s1[rr_], 0.0f);                         \
        acc[2][rr_] += wv[rr_] * fmaxf(s2[rr_], 0.0f);                         \
        acc[3][rr_] += wv[rr_] * fmaxf(s3[rr_], 0.0f);                         \
        acc[4][rr_] += wv[rr_] * fmaxf(s4[rr_], 0.0f);                         \
        acc[5][rr_] += wv[rr_] * fmaxf(s5[rr_], 0.0f);                         \
        acc[6][rr_] += wv[rr_] * fmaxf(s6[rr_], 0.0f);                         \
        acc[7][rr_] += wv[rr_] * fmaxf(s7[rr_], 0.0f);                         \
    }                                                                          \
}

__global__ __launch_bounds__(256)
void scores_mfma(const unsigned char* __restrict__ qfrag,
                 const unsigned char* __restrict__ kfrag,
                 const float* __restrict__ wT, float* __restrict__ S) {
    const int bid = blockIdx.x;                  // 0..1055
    int u = (int)((sqrtf(4.f * bid + 1.f) - 1.f) * 0.5f);
    while ((u + 1) * (u + 2) <= bid) ++u;
    while (u * (u + 1) > bid) --u;
    int r_ = bid - u * (u + 1);                  // 0..2u+1
    const int byp = (r_ <= u) ? 2 * u : 2 * u + 1;
    const int jt  = (r_ <= u) ? r_ : r_ - (u + 1);
    __shared__ float wlds[64][64];
    const int tid = threadIdx.x;
    const int lane = tid & 63, wid = tid >> 6;   // wave = ig owner (0..3)
    const int i0 = byp * 64, j0 = jt * 128;
    const f32x4 zed = {0.f, 0.f, 0.f, 0.f};
#pragma unroll
    for (int it = 0; it < 16; ++it) {
        int fid = it * 256 + tid;
        int hh = fid >> 6, rl = fid & 63;
        wlds[hh][rl] = wT[(size_t)hh * T_DIM + i0 + rl];
    }
    i32x8 kf8[8];
#pragma unroll
    for (int n = 0; n < 8; ++n) {
        int jg = (j0 >> 4) + n;
        kf8[n] = *(const i32x8*)(kfrag + ((size_t)jg * 64 + lane) * 32);
    }
    __syncthreads();

    f32x4 acc[8];
#pragma unroll
    for (int n = 0; n < 8; n++) acc[n] = zed;

    const int rsub = (lane >> 4) << 2;
    const unsigned char* qb = qfrag + (size_t)(byp * 4 + wid) * 131072 + lane * 32;

    i32x8 a0 = *(const i32x8*)qb;
    for (int h = 0; h < NH; h += 2) {
        i32x8 a1 = *(const i32x8*)(qb + (size_t)(h + 1) * 2048);
        SCOMP(a0, h)
        if (h + 2 < NH) a0 = *(const i32x8*)(qb + (size_t)(h + 2) * 2048);
        SCOMP(a1, h + 1)
    }

    const int colc = lane & 15;
#pragma unroll
    for (int n = 0; n < 8; n++) {
        int col = j0 + n * 16 + colc;
#pragma unroll
        for (int rr = 0; rr < 4; rr++) {
            int row = i0 + wid * 16 + rsub + rr;
            float v = acc[n][rr];
            if (col > row) v = MASK_VAL;
            S[(size_t)row * T_DIM + col] = v;
        }
    }
}

// ============================================================================
// topk v7: E=8 keys/thread bitonic (verified round 21)
// ============================================================================
__device__ __forceinline__ void ce(unsigned &x, unsigned &y, bool up) {
    unsigned lo = x < y ? x : y, hi = x < y ? y : x;
    x = up ? lo : hi; y = up ? hi : lo;
}
__device__ __forceinline__ unsigned cd(unsigned a, unsigned b, bool keep_lo) {
    unsigned lo = a < b ? a : b, hi = a < b ? b : a;
    return keep_lo ? lo : hi;
}

#define CE8S(k, j) {                                                           \
    const bool kl_ = ((e0 & (k)) == 0u) ^ ((e0 & (j)) != 0u);                  \
    q0 = cd(q0, (unsigned)__shfl_xor((int)q0, (j) >> 3), kl_);                 \
    q1 = cd(q1, (unsigned)__shfl_xor((int)q1, (j) >> 3), kl_);                 \
    q2 = cd(q2, (unsigned)__shfl_xor((int)q2, (j) >> 3), kl_);                 \
    q3 = cd(q3, (unsigned)__shfl_xor((int)q3, (j) >> 3), kl_);                 \
    q4 = cd(q4, (unsigned)__shfl_xor((int)q4, (j) >> 3), kl_);                 \
    q5 = cd(q5, (unsigned)__shfl_xor((int)q5, (j) >> 3), kl_);                 \
    q6 = cd(q6, (unsigned)__shfl_xor((int)q6, (j) >> 3), kl_);                 \
    q7 = cd(q7, (unsigned)__shfl_xor((int)q7, (j) >> 3), kl_); }

#define CE8R(k) {                                                              \
    const bool up_ = ((e0 & (k)) == 0u);                                       \
    ce(q0, q4, up_); ce(q1, q5, up_); ce(q2, q6, up_); ce(q3, q7, up_);        \
    ce(q0, q2, up_); ce(q1, q3, up_); ce(q4, q6, up_); ce(q5, q7, up_);        \
    ce(q0, q1, up_); ce(q2, q3, up_); ce(q4, q5, up_); ce(q6, q7, up_); }

#define CE8L(k, j) {                                                           \
    __syncthreads();                                                           \
    *(uint4*)&L[e0]     = make_uint4(q0, q1, q2, q3);                          \
    *(uint4*)&L[e0 + 4] = make_uint4(q4, q5, q6, q7);                          \
    __syncthreads();                                                           \
    uint4 pA_ = *(uint4*)&L[(e0 ^ (j))];                                       \
    uint4 pB_ = *(uint4*)&L[(e0 ^ (j)) + 4];                                   \
    const bool kl_ = ((e0 & (k)) == 0u) ^ ((e0 & (j)) != 0u);                  \
    q0 = cd(q0, pA_.x, kl_); q1 = cd(q1, pA_.y, kl_);                          \
    q2 = cd(q2, pA_.z, kl_); q3 = cd(q3, pA_.w, kl_);                          \
    q4 = cd(q4, pB_.x, kl_); q5 = cd(q5, pB_.y, kl_);                          \
    q6 = cd(q6, pB_.z, kl_); q7 = cd(q7, pB_.w, kl_); }

#define CM8L(j) {                                                              \
    __syncthreads();                                                           \
    if (low) {                                                                 \
        *(uint4*)&L[e0]     = make_uint4(q0, q1, q2, q3);                      \
        *(uint4*)&L[e0 + 4] = make_uint4(q4, q5, q6, q7);                      \
    }                                                                          \
    __syncthreads();                                                           \
    if (low) {                                                                 \
        uint4 pA_ = *(uint4*)&L[(e0 ^ (j))];                                   \
        uint4 pB_ = *(uint4*)&L[(e0 ^ (j)) + 4];                               \
        const bool kl_ = (e0 & (j)) == 0u;                                     \
        q0 = cd(q0, pA_.x, kl_); q1 = cd(q1, pA_.y, kl_);                      \
        q2 = cd(q2, pA_.z, kl_); q3 = cd(q3, pA_.w, kl_);                      \
        q4 = cd(q4, pB_.x, kl_); q5 = cd(q5, pB_.y, kl_);                      \
        q6 = cd(q6, pB_.z, kl_); q7 = cd(q7, pB_.w, kl_); } }

#define CM8S(j) {                                                              \
    const bool kl_ = (e0 & (j)) == 0u;                                         \
    q0 = cd(q0, (unsigned)__shfl_xor((int)q0, (j) >> 3), kl_);                 \
    q1 = cd(q1, (unsigned)__shfl_xor((int)q1, (j) >> 3), kl_);                 \
    q2 = cd(q2, (unsigned)__shfl_xor((int)q2, (j) >> 3), kl_);                 \
    q3 = cd(q3, (unsigned)__shfl_xor((int)q3, (j) >> 3), kl_);                 \
    q4 = cd(q4, (unsigned)__shfl_xor((int)q4, (j) >> 3), kl_);                 \
    q5 = cd(q5, (unsigned)__shfl_xor((int)q5, (j) >> 3), kl_);                 \
    q6 = cd(q6, (unsigned)__shfl_xor((int)q6, (j) >> 3), kl_);                 \
    q7 = cd(q7, (unsigned)__shfl_xor((int)q7, (j) >> 3), kl_); }

__global__ __launch_bounds__(1024)
void topk_kernel(const float* __restrict__ S, float* __restrict__ outIdx) {
    __shared__ unsigned lds[8192];
    const int bid = blockIdx.x;
    const int tid = threadIdx.x;

    int row; unsigned e0; unsigned* L; bool longrow;
    if (bid < 512) {             // 4 short rows (row < 2048), 256 thr each
        int slot = tid >> 8;
        row = bid * 4 + slot;
        e0 = 8u * (tid & 255);
        L = &lds[slot * 2048];
        longrow = false;
    } else {                     // 2 long rows, 512 thr each
        int slot = tid >> 9;
        row = 2048 + (bid - 512) * 2 + slot;
        e0 = 8u * (tid & 511);
        L = &lds[slot * 4096];
        longrow = true;
    }

    unsigned q0, q1, q2, q3, q4, q5, q6, q7;
    {   // load 8 keys + mask synth
        float4 f0 = *(const float4*)(S + (size_t)row * T_DIM + e0);
        float4 f1 = *(const float4*)(S + (size_t)row * T_DIM + e0 + 4);
        const float fp[8] = {f0.x, f0.y, f0.z, f0.w, f1.x, f1.y, f1.z, f1.w};
        unsigned qq[8];
#pragma unroll
        for (int e = 0; e < 8; ++e) {
            unsigned p = e0 + e;
            unsigned u = __float_as_uint(fp[e]);
            u = (u & 0x80000000u) ? ~u : (u | 0x80000000u);
            unsigned key = ((~u) & 0xFFFFF000u) | p;
            qq[e] = ((int)p > row) ? (0xFFFFF000u | p) : key;
        }
        q0 = qq[0]; q1 = qq[1]; q2 = qq[2]; q3 = qq[3];
        q4 = qq[4]; q5 = qq[5]; q6 = qq[6]; q7 = qq[7];
    }
    // in-thread stages k=2,4,8 (directions from global index bits)
    ce(q0, q1, true);  ce(q2, q3, false); ce(q4, q5, true);  ce(q6, q7, false);
    ce(q0, q2, true);  ce(q1, q3, true);  ce(q4, q6, false); ce(q5, q7, false);
    ce(q0, q1, true);  ce(q2, q3, true);  ce(q4, q5, false); ce(q6, q7, false);
    {
        const bool up8 = ((e0 & 8u) == 0u);
        ce(q0, q4, up8); ce(q1, q5, up8); ce(q2, q6, up8); ce(q3, q7, up8);
        ce(q0, q2, up8); ce(q1, q3, up8); ce(q4, q6, up8); ce(q5, q7, up8);
        ce(q0, q1, up8); ce(q2, q3, up8); ce(q4, q5, up8); ce(q6, q7, up8);
    }
    // stages k=16..2048
    CE8S(16u, 8u)                                                CE8R(16u)
    CE8S(32u, 16u)  CE8S(32u, 8u)                                CE8R(32u)
    CE8S(64u, 32u)  CE8S(64u, 16u)  CE8S(64u, 8u)                CE8R(64u)
    CE8S(128u, 64u) CE8S(128u, 32u) CE8S(128u, 16u) CE8S(128u, 8u) CE8R(128u)
    CE8S(256u, 128u) CE8S(256u, 64u) CE8S(256u, 32u)
    CE8S(256u, 16u)  CE8S(256u, 8u)                              CE8R(256u)
    CE8S(512u, 256u) CE8S(512u, 128u) CE8S(512u, 64u)
    CE8S(512u, 32u)  CE8S(512u, 16u)  CE8S(512u, 8u)             CE8R(512u)
    CE8L(1024u, 512u)
    CE8S(1024u, 256u) CE8S(1024u, 128u) CE8S(1024u, 64u)
    CE8S(1024u, 32u)  CE8S(1024u, 16u)  CE8S(1024u, 8u)          CE8R(1024u)
    CE8L(2048u, 1024u) CE8L(2048u, 512u)
    CE8S(2048u, 256u) CE8S(2048u, 128u) CE8S(2048u, 64u)
    CE8S(2048u, 32u)  CE8S(2048u, 16u)  CE8S(2048u, 8u)          CE8R(2048u)

    if (!longrow) {
        float4 o0 = make_float4((float)(q0 & 0xFFFu), (float)(q1 & 0xFFFu),
                                (float)(q2 & 0xFFFu), (float)(q3 & 0xFFFu));
        float4 o1 = make_float4((float)(q4 & 0xFFFu), (float)(q5 & 0xFFFu),
                                (float)(q6 & 0xFFFu), (float)(q7 & 0xFFFu));
        *(float4*)(outIdx + (size_t)row * TOPK_N + e0) = o0;
        *(float4*)(outIdx + (size_t)row * TOPK_N + e0 + 4) = o1;
    } else {
        // merge k=4096: mins into lower 2048, then ascending clean of lower.
        __syncthreads();
        *(uint4*)&L[e0]     = make_uint4(q0, q1, q2, q3);
        *(uint4*)&L[e0 + 4] = make_uint4(q4, q5, q6, q7);
        __syncthreads();
        const bool low = e0 < 2048u;
        if (low) {
            uint4 pA = *(uint4*)&L[e0 + 2048];
            uint4 pB = *(uint4*)&L[e0 + 2048 + 4];
            q0 = q0 < pA.x ? q0 : pA.x; q1 = q1 < pA.y ? q1 : pA.y;
            q2 = q2 < pA.z ? q2 : pA.z; q3 = q3 < pA.w ? q3 : pA.w;
            q4 = q4 < pB.x ? q4 : pB.x; q5 = q5 < pB.y ? q5 : pB.y;
            q6 = q6 < pB.z ? q6 : pB.z; q7 = q7 < pB.w ? q7 : pB.w;
        }
        CM8L(1024u) CM8L(512u)
        if (low) {
            CM8S(256u) CM8S(128u) CM8S(64u) CM8S(32u) CM8S(16u) CM8S(8u)
            ce(q0, q4, true); ce(q1, q5, true); ce(q2, q6, true); ce(q3, q7, true);
            ce(q0, q2, true); ce(q1, q3, true); ce(q4, q6, true); ce(q5, q7, true);
            ce(q0, q1, true); ce(q2, q3, true); ce(q4, q5, true); ce(q6, q7, true);
            float4 o0 = make_float4((float)(q0 & 0xFFFu), (float)(q1 & 0xFFFu),
                                    (float)(q2 & 0xFFFu), (float)(q3 & 0xFFFu));
            float4 o1 = make_float4((float)(q4 & 0xFFFu), (float)(q5 & 0xFFFu),
                                    (float)(q6 & 0xFFFu), (float)(q7 & 0xFFFu));
            *(float4*)(outIdx + (size_t)row * TOPK_N + e0) = o0;
            *(float4*)(outIdx + (size_t)row * TOPK_N + e0 + 4) = o1;
        }
    }
}

// ============================================================================
extern "C" void kernel_launch(void* const* d_in, const int* in_sizes, int n_in,
                              void* d_out, int out_size, void* d_ws, size_t ws_size,
                              hipStream_t stream) {
    const float* hs      = (const float*)d_in[0];
    const float* qr      = (const float*)d_in[1];
    const int*   pos     = (const int*)  d_in[2];
    const float* wq_b    = (const float*)d_in[3];
    const float* wk      = (const float*)d_in[4];
    const float* k_gamma = (const float*)d_in[5];
    const float* k_beta  = (const float*)d_in[6];
    const float* w_proj  = (const float*)d_in[7];

    float* out     = (float*)d_out;
    float* out_idx = out;
    float* S       = out + (size_t)T_DIM * TOPK_N;

    char* wsp = (char*)d_ws;
    unsigned char*  qfrag  = (unsigned char*)wsp;  wsp += (size_t)67108864;
    unsigned short* hsfrag = (unsigned short*)qfrag;  // alias: hs consumed before qfrag written
    unsigned char*  qrfrag = (unsigned char*)wsp;  wsp += (size_t)12582912;
    unsigned char*  wqfrag = (unsigned char*)wsp;  wsp += (size_t)25165824;
    unsigned short* wkwfrag= (unsigned short*)wsp; wsp += (size_t)2752512;
    float*          part   = (float*)wsp;          wsp += (size_t)12582912;
    float*          wT     = (float*)wsp;          wsp += (size_t)1048576;
    unsigned char*  kfrag  = (unsigned char*)wsp;  wsp += (size_t)1048576;
    float2*         tab    = (float2*)wsp;         wsp += (size_t)1048576;

    rope_tab_kernel<<<512, 256, 0, stream>>>(pos, tab);
    conv_afrag <<<3584, 256, 0, stream>>>(hs, hsfrag, HSZ, 224, 28);
    conv_wkw   <<<672,  256, 0, stream>>>(wk, w_proj, wkwfrag);
    kw_gemm_mfma<<<1024, 256, 0, stream>>>(hsfrag, wkwfrag, part);
    reduce_w   <<<64,   256, 0, stream>>>(part, wT);
    ln_rope_k  <<<T_DIM / 4, 256, 0, stream>>>(part, tab, k_gamma, k_beta, kfrag);
    conv_qr_fp8<<<768,  256, 0, stream>>>(qr, qrfrag);
    conv_wq_fp8<<<1536, 256, 0, stream>>>(wq_b, wqfrag);
    q_gemm_mfma<<<2048, 256, 0, stream>>>(qrfrag, wqfrag, tab, qfrag);
    scores_mfma<<<1056, 256, 0, stream>>>(qfrag, kfrag, wT, S);
    topk_kernel<<<1536, 1024, 0, stream>>>(S, out_idx);
}